// Round 12
// baseline (421.027 us; speedup 1.0000x reference)
//
#include <hip/hip_runtime.h>
#include <hip/hip_bf16.h>
#include <cfloat>

#define N_NODES 50000
#define N_EDGES 800000
#define E_TOT   850000   /* edges + self-loops */
#define NEG_SLOPE 0.2f
#define SM_EPS 1e-16f
#define SCAN_B 196       /* ceil(50000/256) */

__device__ __forceinline__ float lrelu(float v) { return v > 0.0f ? v : NEG_SLOPE * v; }

// fp32 -> bf16 bits (RNE) and back, via integer ops (no type plumbing)
__device__ __forceinline__ unsigned f2bf_pack2(float a, float b) {
    unsigned ua = __float_as_uint(a);
    ua += 0x7fff + ((ua >> 16) & 1);
    unsigned ub = __float_as_uint(b);
    ub += 0x7fff + ((ub >> 16) & 1);
    return (ua >> 16) | (ub & 0xffff0000u);
}
__device__ __forceinline__ float bf_lo(unsigned u) { return __uint_as_float(u << 16); }
__device__ __forceinline__ float bf_hi(unsigned u) { return __uint_as_float(u & 0xffff0000u); }

// ---- CSR build -------------------------------------------------------------
// Layout detect (per block): int64 edge_index has all odd 32-bit words zero
// (ids < 50000); int32 layout has random src ids there. 256 probes -> exact.

// One atomic pass: histogram + per-edge rank (r = old count). rank16 written
// sequentially; scatter pass then needs NO atomics.
__global__ void count_deg(const int* __restrict__ ei, int* __restrict__ deg,
                          unsigned short* __restrict__ rank16) {
    int nz = __syncthreads_or(ei[2 * threadIdx.x + 1]);   // 0 => int64 layout
    int i = blockIdx.x * blockDim.x + threadIdx.x;        // edge-pair index
    if (2 * i >= N_EDGES) return;
    bool has2 = (2 * i + 1 < N_EDGES);
    int d0, d1 = 0;
    if (nz) {  // int32: [src[E], dst[E]]
        int2 dp = *(const int2*)(ei + N_EDGES + 2 * i);
        d0 = dp.x; d1 = dp.y;
    } else {   // int64: lo words at even indices
        int4 dp = *(const int4*)(ei + 2 * N_EDGES + 4 * i);
        d0 = dp.x; d1 = dp.z;
    }
    unsigned short r0 = (unsigned short)atomicAdd(&deg[d0], 1);
    unsigned short r1 = 0;
    if (has2) r1 = (unsigned short)atomicAdd(&deg[d1], 1);
    *(unsigned int*)(rank16 + 2 * i) = (unsigned int)r0 | ((unsigned int)r1 << 16);
}

// blocked exclusive scan; +1 per node folds in the self-loop
__global__ void scan_local(const int* __restrict__ deg, int* __restrict__ rowptr,
                           int* __restrict__ bsum) {
    __shared__ int sh[256];
    int b = blockIdx.x, t = threadIdx.x, i = b * 256 + t;
    int v = (i < N_NODES) ? deg[i] + 1 : 0;
    sh[t] = v;
    __syncthreads();
    int val = v;
    for (int off = 1; off < 256; off <<= 1) {
        int add = (t >= off) ? sh[t - off] : 0;
        __syncthreads();
        val += add; sh[t] = val;
        __syncthreads();
    }
    if (i < N_NODES) rowptr[i] = val - v;
    if (t == 255) bsum[b] = val;
}

// add block offsets (local tree-sum over preceding block sums);
// write self-loop into slot 0 of each node's segment
__global__ void scan_add(int* __restrict__ rowptr, const int* __restrict__ bsum,
                         int* __restrict__ esrc) {
    __shared__ int sh[256];
    int b = blockIdx.x, t = threadIdx.x;
    sh[t] = (t < b && t < SCAN_B) ? bsum[t] : 0;
    __syncthreads();
    #pragma unroll
    for (int off = 128; off; off >>= 1) {
        if (t < off) sh[t] += sh[t + off];
        __syncthreads();
    }
    int offset = sh[0];
    int i = b * 256 + t;
    if (i < N_NODES) {
        int rp = rowptr[i] + offset;
        rowptr[i] = rp;
        esrc[rp] = i;       // self-loop first
    }
    if (i == 0) rowptr[N_NODES] = E_TOT;
}

// no atomics: position = rowptr[dst] + 1 + rank
__global__ void scatter_edges(const int* __restrict__ ei, const int* __restrict__ rowptr,
                              const unsigned short* __restrict__ rank16,
                              int* __restrict__ esrc) {
    int nz = __syncthreads_or(ei[2 * threadIdx.x + 1]);
    int i = blockIdx.x * blockDim.x + threadIdx.x;
    if (2 * i >= N_EDGES) return;
    bool has2 = (2 * i + 1 < N_EDGES);
    int s0, d0, s1 = 0, d1 = 0;
    if (nz) {
        int2 sp = *(const int2*)(ei + 2 * i);
        int2 dp = *(const int2*)(ei + N_EDGES + 2 * i);
        s0 = sp.x; s1 = sp.y; d0 = dp.x; d1 = dp.y;
    } else {
        int4 sp = *(const int4*)(ei + 4 * i);
        int4 dp = *(const int4*)(ei + 2 * N_EDGES + 4 * i);
        s0 = sp.x; s1 = sp.z; d0 = dp.x; d1 = dp.z;
    }
    unsigned int rr = *(const unsigned int*)(rank16 + 2 * i);
    esrc[rowptr[d0] + 1 + (int)(rr & 0xffffu)] = s0;
    if (has2) esrc[rowptr[d1] + 1 + (int)(rr >> 16)] = s1;
}

// ---------------- GEMM pair: C0 = A@B0, C1 = A@B1 ; A[M,128], B[128,N] ----------------
// 256 threads, 32 rows/block. B staged in LDS as bf16, K-blocked in halves of 64:
// the k-loop is pure LDS + FMA (no global latency). A staged fp32 transposed.
template<int N>
__global__ __launch_bounds__(256)
void gemm_pair(const float* __restrict__ A, const float* __restrict__ B0,
               const float* __restrict__ B1, float* __restrict__ C0,
               float* __restrict__ C1, int M) {
    constexpr int JQ  = N / 4;          // col quads per matrix (32 / 16)
    constexpr int RG  = 128 / JQ;       // row groups (threads = JQ*RG*2 = 256)
    constexpr int RPT = 32 / RG;        // rows per thread (8 for N=128, 4 for N=64)
    __shared__ float aT[128][36];                    // 18.4 KB
    __shared__ unsigned short bS[2 * 64 * N];        // 32 KB (N=128) / 16 KB (N=64)
    int t = threadIdx.x;
    int jq    = t % JQ;
    int rg    = (t / JQ) % RG;
    int which = t / 128;
    float*       C = which ? C1 : C0;
    int row0 = blockIdx.x * 32;
    for (int i = t; i < 32 * 128; i += 256) {
        int r = i >> 7, kk = i & 127;
        int row = row0 + r;
        aT[kk][r] = (row < M) ? A[(size_t)row * 128 + kk] : 0.0f;
    }
    float acc[RPT][4];
    #pragma unroll
    for (int r = 0; r < RPT; ++r)
        #pragma unroll
        for (int c = 0; c < 4; ++c) acc[r][c] = 0.0f;
    const int rbase = rg * RPT;
    const unsigned short* myB = bS + which * 64 * N + jq * 4;
    for (int kb = 0; kb < 2; ++kb) {
        __syncthreads();   // kb=0: finalize A staging; kb=1: drain bS readers
        constexpr int QTOT = 2 * 64 * (N / 4);
        for (int i = t; i < QTOT; i += 256) {
            int wb  = i / (64 * (N / 4));
            int rem = i % (64 * (N / 4));
            int kl  = rem / (N / 4);
            int qc  = rem % (N / 4);
            const float* src = (wb ? B1 : B0) + (size_t)(kb * 64 + kl) * N + qc * 4;
            float4 f = *(const float4*)src;
            uint2 pk;
            pk.x = f2bf_pack2(f.x, f.y);
            pk.y = f2bf_pack2(f.z, f.w);
            *(uint2*)(bS + wb * 64 * N + kl * N + qc * 4) = pk;
        }
        __syncthreads();
        for (int kl = 0; kl < 64; kl += 2) {
            int kg = kb * 64 + kl;
            uint2 u0 = *(const uint2*)(myB + (size_t)kl * N);
            uint2 u1 = *(const uint2*)(myB + (size_t)(kl + 1) * N);
            float av0[RPT], av1[RPT];
            #pragma unroll
            for (int q = 0; q < RPT; q += 4) {
                *(float4*)&av0[q] = *(const float4*)&aT[kg][rbase + q];
                *(float4*)&av1[q] = *(const float4*)&aT[kg + 1][rbase + q];
            }
            float bx0 = bf_lo(u0.x), by0 = bf_hi(u0.x), bz0 = bf_lo(u0.y), bw0 = bf_hi(u0.y);
            float bx1 = bf_lo(u1.x), by1 = bf_hi(u1.x), bz1 = bf_lo(u1.y), bw1 = bf_hi(u1.y);
            #pragma unroll
            for (int r = 0; r < RPT; ++r) {
                acc[r][0] += av0[r] * bx0; acc[r][1] += av0[r] * by0;
                acc[r][2] += av0[r] * bz0; acc[r][3] += av0[r] * bw0;
            }
            #pragma unroll
            for (int r = 0; r < RPT; ++r) {
                acc[r][0] += av1[r] * bx1; acc[r][1] += av1[r] * by1;
                acc[r][2] += av1[r] * bz1; acc[r][3] += av1[r] * bw1;
            }
        }
    }
    #pragma unroll
    for (int r = 0; r < RPT; ++r) {
        int row = row0 + rbase + r;
        if (row < M) {
            float4 o; o.x = acc[r][0]; o.y = acc[r][1]; o.z = acc[r][2]; o.w = acc[r][3];
            *(float4*)(C + (size_t)row * N + jq * 4) = o;
        }
    }
}

// ---------------- Layer 1 (H=8, C=16) ----------------
// Node per wave; wave = 4 edge-slots x 16 lanes; lane holds 8 channels (2xfloat4).
__global__ __launch_bounds__(256)
void node_fused1(const int* __restrict__ rowptr, const int* __restrict__ esrc,
                 const float* __restrict__ xl, const float* __restrict__ xr,
                 const float* __restrict__ att, const float* __restrict__ b1,
                 float* __restrict__ hout) {
    int wave = threadIdx.x >> 6;
    int lane = threadIdx.x & 63;
    int n = blockIdx.x * 4 + wave;            // grid = 12500 exact
    int slot = lane >> 4;                     // 0..3
    int l = lane & 15;                        // channels 8l..8l+7
    int beg = rowptr[n], end = rowptr[n + 1];
    const float* xrp = xr + (size_t)n * 128 + 8 * l;
    float4 xra = *(const float4*)(xrp);
    float4 xrb = *(const float4*)(xrp + 4);
    float4 ata = *(const float4*)(att + 8 * l);
    float4 atb = *(const float4*)(att + 8 * l + 4);
    float den = 0.0f;
    float4 aa = {0, 0, 0, 0}, ab = {0, 0, 0, 0};

    auto body = [&](int k) {
        int s = esrc[k];
        const float* xp = xl + (size_t)s * 128 + 8 * l;
        float4 xa = *(const float4*)(xp);
        float4 xb = *(const float4*)(xp + 4);
        float v = ata.x * lrelu(xa.x + xra.x) + ata.y * lrelu(xa.y + xra.y)
                + ata.z * lrelu(xa.z + xra.z) + ata.w * lrelu(xa.w + xra.w)
                + atb.x * lrelu(xb.x + xrb.x) + atb.y * lrelu(xb.y + xrb.y)
                + atb.z * lrelu(xb.z + xrb.z) + atb.w * lrelu(xb.w + xrb.w);
        v += __shfl_xor(v, 1);                // combine the head's two lanes
        float p = __expf(v);
        den += p;
        aa.x += p * xa.x; aa.y += p * xa.y; aa.z += p * xa.z; aa.w += p * xa.w;
        ab.x += p * xb.x; ab.y += p * xb.y; ab.z += p * xb.z; ab.w += p * xb.w;
    };
    int k = beg + slot;
    for (; k + 4 < end; k += 8) { body(k); body(k + 4); }
    if (k < end) body(k);

    // merge 4 slots
    #pragma unroll
    for (int off = 16; off < 64; off <<= 1) {
        aa.x += __shfl_xor(aa.x, off); aa.y += __shfl_xor(aa.y, off);
        aa.z += __shfl_xor(aa.z, off); aa.w += __shfl_xor(aa.w, off);
        ab.x += __shfl_xor(ab.x, off); ab.y += __shfl_xor(ab.y, off);
        ab.z += __shfl_xor(ab.z, off); ab.w += __shfl_xor(ab.w, off);
        den   += __shfl_xor(den, off);
    }
    if (slot == 0) {
        float inv = 1.0f / (den + SM_EPS);
        float4 b4a = *(const float4*)(b1 + 8 * l);
        float4 b4b = *(const float4*)(b1 + 8 * l + 4);
        float4 oa, ob;
        oa.x = fmaxf(aa.x * inv + b4a.x, 0.0f);
        oa.y = fmaxf(aa.y * inv + b4a.y, 0.0f);
        oa.z = fmaxf(aa.z * inv + b4a.z, 0.0f);
        oa.w = fmaxf(aa.w * inv + b4a.w, 0.0f);
        ob.x = fmaxf(ab.x * inv + b4b.x, 0.0f);
        ob.y = fmaxf(ab.y * inv + b4b.y, 0.0f);
        ob.z = fmaxf(ab.z * inv + b4b.z, 0.0f);
        ob.w = fmaxf(ab.w * inv + b4b.w, 0.0f);
        float* op = hout + (size_t)n * 128 + 8 * l;
        *(float4*)(op)     = oa;
        *(float4*)(op + 4) = ob;
    }
}

// ---------------- Layer 2 (H=1, C=64) ----------------
// Node per wave; wave = 8 edge-slots x 8 lanes; lane holds 8 channels.
__global__ __launch_bounds__(256)
void node_fused2(const int* __restrict__ rowptr, const int* __restrict__ esrc,
                 const float* __restrict__ xl, const float* __restrict__ xr,
                 const float* __restrict__ att, const float* __restrict__ b2v,
                 float* __restrict__ out_emb) {
    int wave = threadIdx.x >> 6;
    int lane = threadIdx.x & 63;
    int n = blockIdx.x * 4 + wave;
    int slot = lane >> 3;                     // 0..7
    int l = lane & 7;                         // channels 8l..8l+7
    int beg = rowptr[n], end = rowptr[n + 1];
    const float* xrp = xr + (size_t)n * 64 + 8 * l;
    float4 xra = *(const float4*)(xrp);
    float4 xrb = *(const float4*)(xrp + 4);
    float4 ata = *(const float4*)(att + 8 * l);
    float4 atb = *(const float4*)(att + 8 * l + 4);
    float den = 0.0f;
    float4 aa = {0, 0, 0, 0}, ab = {0, 0, 0, 0};

    auto body = [&](int k) {
        int s = esrc[k];
        const float* xp = xl + (size_t)s * 64 + 8 * l;
        float4 xa = *(const float4*)(xp);
        float4 xb = *(const float4*)(xp + 4);
        float v = ata.x * lrelu(xa.x + xra.x) + ata.y * lrelu(xa.y + xra.y)
                + ata.z * lrelu(xa.z + xra.z) + ata.w * lrelu(xa.w + xra.w)
                + atb.x * lrelu(xb.x + xrb.x) + atb.y * lrelu(xb.y + xrb.y)
                + atb.z * lrelu(xb.z + xrb.z) + atb.w * lrelu(xb.w + xrb.w);
        v += __shfl_xor(v, 1);
        v += __shfl_xor(v, 2);
        v += __shfl_xor(v, 4);
        float p = __expf(v);
        den += p;
        aa.x += p * xa.x; aa.y += p * xa.y; aa.z += p * xa.z; aa.w += p * xa.w;
        ab.x += p * xb.x; ab.y += p * xb.y; ab.z += p * xb.z; ab.w += p * xb.w;
    };
    int k = beg + slot;
    for (; k + 8 < end; k += 16) { body(k); body(k + 8); }
    if (k < end) body(k);

    // merge 8 slots
    #pragma unroll
    for (int off = 8; off < 64; off <<= 1) {
        aa.x += __shfl_xor(aa.x, off); aa.y += __shfl_xor(aa.y, off);
        aa.z += __shfl_xor(aa.z, off); aa.w += __shfl_xor(aa.w, off);
        ab.x += __shfl_xor(ab.x, off); ab.y += __shfl_xor(ab.y, off);
        ab.z += __shfl_xor(ab.z, off); ab.w += __shfl_xor(ab.w, off);
        den   += __shfl_xor(den, off);
    }
    if (slot == 0) {
        float inv = 1.0f / (den + SM_EPS);
        float4 b4a = *(const float4*)(b2v + 8 * l);
        float4 b4b = *(const float4*)(b2v + 8 * l + 4);
        float4 ea, eb;
        ea.x = aa.x * inv + b4a.x; ea.y = aa.y * inv + b4a.y;
        ea.z = aa.z * inv + b4a.z; ea.w = aa.w * inv + b4a.w;
        eb.x = ab.x * inv + b4b.x; eb.y = ab.y * inv + b4b.y;
        eb.z = ab.z * inv + b4b.z; eb.w = ab.w * inv + b4b.w;
        float* op = out_emb + (size_t)n * 64 + 8 * l;
        *(float4*)(op)     = ea;
        *(float4*)(op + 4) = eb;
    }
}

// ---------------- Classifier: LDS-tiled ----------------
#define CLS_NODES 32
__global__ __launch_bounds__(256)
void classifier(const float* __restrict__ emb, const float* __restrict__ Wc1,
                const float* __restrict__ bc1, const float* __restrict__ Wc2,
                const float* __restrict__ bc2, float* __restrict__ out_logits) {
    __shared__ float w1[64 * 128];            // 32 KB
    __shared__ float eS[CLS_NODES][64];       // 8 KB
    __shared__ float tS[CLS_NODES][132];      // pad 132 breaks phase-C conflicts
    int t = threadIdx.x;
    int n0 = blockIdx.x * CLS_NODES;
    for (int i = t; i < 64 * 128 / 4; i += 256)
        ((float4*)w1)[i] = ((const float4*)Wc1)[i];
    for (int i = t; i < CLS_NODES * 64 / 4; i += 256) {
        size_t off = (size_t)n0 * 64 + i * 4;
        float4 v = {0, 0, 0, 0};
        if (off + 3 < (size_t)N_NODES * 64) v = *(const float4*)(emb + off);
        ((float4*)eS)[i] = v;
    }
    __syncthreads();
    int jj = t & 127, half = t >> 7;
    for (int nn = half; nn < CLS_NODES; nn += 2) {
        float a0 = 0, a1 = 0, a2 = 0, a3 = 0;
        #pragma unroll
        for (int k = 0; k < 64; k += 4) {
            a0 += eS[nn][k]     * w1[(k)     * 128 + jj];
            a1 += eS[nn][k + 1] * w1[(k + 1) * 128 + jj];
            a2 += eS[nn][k + 2] * w1[(k + 2) * 128 + jj];
            a3 += eS[nn][k + 3] * w1[(k + 3) * 128 + jj];
        }
        tS[nn][jj] = fmaxf(bc1[jj] + (a0 + a1) + (a2 + a3), 0.0f);
    }
    __syncthreads();
    int node = t >> 3, seg = t & 7;
    float v0 = 0, v1 = 0;
    #pragma unroll
    for (int c = 0; c < 16; ++c) {
        float tv = tS[node][seg * 16 + c];
        v0 += tv * Wc2[2 * (seg * 16 + c)];
        v1 += tv * Wc2[2 * (seg * 16 + c) + 1];
    }
    v0 += __shfl_xor(v0, 1); v1 += __shfl_xor(v1, 1);
    v0 += __shfl_xor(v0, 2); v1 += __shfl_xor(v1, 2);
    v0 += __shfl_xor(v0, 4); v1 += __shfl_xor(v1, 4);
    int n = n0 + node;
    if (seg == 0 && n < N_NODES) {
        out_logits[(size_t)n * 2 + 0] = v0 + bc2[0];
        out_logits[(size_t)n * 2 + 1] = v1 + bc2[1];
    }
}

extern "C" void kernel_launch(void* const* d_in, const int* in_sizes, int n_in,
                              void* d_out, int out_size, void* d_ws, size_t ws_size,
                              hipStream_t stream) {
    const float* x    = (const float*)d_in[0];
    const int*   ei   = (const int*)d_in[1];
    const float* Wl1  = (const float*)d_in[3];
    const float* Wr1  = (const float*)d_in[4];
    const float* att1 = (const float*)d_in[5];
    const float* b1   = (const float*)d_in[6];
    const float* Wl2  = (const float*)d_in[7];
    const float* Wr2  = (const float*)d_in[8];
    const float* att2 = (const float*)d_in[9];
    const float* b2   = (const float*)d_in[10];
    const float* Wc1  = (const float*)d_in[15];
    const float* bc1  = (const float*)d_in[16];
    const float* Wc2  = (const float*)d_in[17];
    const float* bc2  = (const float*)d_in[18];

    float* ws = (float*)d_ws;
    int* deg    = (int*)ws;                        //      0 .. 50000 (zeroed by memset)
    int* rowptr = deg + 50000;                     //  50000 .. 100016
    int* esrc   = rowptr + 50016;                  // 100016 .. 950016
    int* bsum   = esrc + 850000;                   // 950016 .. 950272
    unsigned short* rank16 = (unsigned short*)(bsum + 256);  // 800000 u16 -> 400000 ints
    float* xl1  = ws + 1400448;                    // 6.40M (layer2 xl2 in first 3.2M)
    float* xr1  = ws + 7800448;                    // 6.40M (layer2 xr2)
    float* hbuf = ws + 14200448;                   // 6.40M -> ends 20.6M words ≈ 82 MB

    float* out_emb    = (float*)d_out;
    float* out_logits = out_emb + (size_t)N_NODES * 64;

    // ---- CSR build ----
    hipMemsetAsync(deg, 0, 50000 * sizeof(int), stream);
    count_deg<<<1563, 256, 0, stream>>>(ei, deg, rank16);
    scan_local<<<SCAN_B, 256, 0, stream>>>(deg, rowptr, bsum);
    scan_add<<<SCAN_B, 256, 0, stream>>>(rowptr, bsum, esrc);
    scatter_edges<<<1563, 256, 0, stream>>>(ei, rowptr, rank16, esrc);

    // ---- layer 1 ----
    gemm_pair<128><<<1563, 256, 0, stream>>>(x, Wl1, Wr1, xl1, xr1, N_NODES);
    node_fused1<<<12500, 256, 0, stream>>>(rowptr, esrc, xl1, xr1, att1, b1, hbuf);

    // ---- layer 2 ----
    gemm_pair<64><<<1563, 256, 0, stream>>>(hbuf, Wl2, Wr2, xl1, xr1, N_NODES);
    node_fused2<<<12500, 256, 0, stream>>>(rowptr, esrc, xl1, xr1, att2, b2, out_emb);

    // ---- classifier ----
    classifier<<<1563, 256, 0, stream>>>(out_emb, Wc1, bc1, Wc2, bc2, out_logits);
}

// Round 13
// 360.590 us; speedup vs baseline: 1.1676x; 1.1676x over previous
//
#include <hip/hip_runtime.h>
#include <hip/hip_bf16.h>
#include <cfloat>

#define N_NODES 50000
#define N_EDGES 800000
#define E_TOT   850000   /* edges + self-loops */
#define NEG_SLOPE 0.2f
#define SM_EPS 1e-16f
#define SCAN_B 196       /* ceil(50000/256) */

typedef __attribute__((ext_vector_type(8))) short short8;
typedef __attribute__((ext_vector_type(4))) float f32x4;

__device__ __forceinline__ float lrelu(float v) { return v > 0.0f ? v : NEG_SLOPE * v; }

// fp32 -> bf16 (RNE) packing helpers
__device__ __forceinline__ unsigned f2bf_pack2(float a, float b) {
    unsigned ua = __float_as_uint(a);
    ua += 0x7fff + ((ua >> 16) & 1);
    unsigned ub = __float_as_uint(b);
    ub += 0x7fff + ((ub >> 16) & 1);
    return (ua >> 16) | (ub & 0xffff0000u);
}
__device__ __forceinline__ unsigned short f2bf(float a) {
    unsigned ua = __float_as_uint(a);
    ua += 0x7fff + ((ua >> 16) & 1);
    return (unsigned short)(ua >> 16);
}

// ---- CSR build -------------------------------------------------------------
__global__ void count_deg(const int* __restrict__ ei, int* __restrict__ deg,
                          unsigned short* __restrict__ rank16) {
    int nz = __syncthreads_or(ei[2 * threadIdx.x + 1]);   // 0 => int64 layout
    int i = blockIdx.x * blockDim.x + threadIdx.x;        // edge-pair index
    if (2 * i >= N_EDGES) return;
    bool has2 = (2 * i + 1 < N_EDGES);
    int d0, d1 = 0;
    if (nz) {
        int2 dp = *(const int2*)(ei + N_EDGES + 2 * i);
        d0 = dp.x; d1 = dp.y;
    } else {
        int4 dp = *(const int4*)(ei + 2 * N_EDGES + 4 * i);
        d0 = dp.x; d1 = dp.z;
    }
    unsigned short r0 = (unsigned short)atomicAdd(&deg[d0], 1);
    unsigned short r1 = 0;
    if (has2) r1 = (unsigned short)atomicAdd(&deg[d1], 1);
    *(unsigned int*)(rank16 + 2 * i) = (unsigned int)r0 | ((unsigned int)r1 << 16);
}

__global__ void scan_local(const int* __restrict__ deg, int* __restrict__ rowptr,
                           int* __restrict__ bsum) {
    __shared__ int sh[256];
    int b = blockIdx.x, t = threadIdx.x, i = b * 256 + t;
    int v = (i < N_NODES) ? deg[i] + 1 : 0;
    sh[t] = v;
    __syncthreads();
    int val = v;
    for (int off = 1; off < 256; off <<= 1) {
        int add = (t >= off) ? sh[t - off] : 0;
        __syncthreads();
        val += add; sh[t] = val;
        __syncthreads();
    }
    if (i < N_NODES) rowptr[i] = val - v;
    if (t == 255) bsum[b] = val;
}

__global__ void scan_add(int* __restrict__ rowptr, const int* __restrict__ bsum,
                         int* __restrict__ esrc) {
    __shared__ int sh[256];
    int b = blockIdx.x, t = threadIdx.x;
    sh[t] = (t < b && t < SCAN_B) ? bsum[t] : 0;
    __syncthreads();
    #pragma unroll
    for (int off = 128; off; off >>= 1) {
        if (t < off) sh[t] += sh[t + off];
        __syncthreads();
    }
    int offset = sh[0];
    int i = b * 256 + t;
    if (i < N_NODES) {
        int rp = rowptr[i] + offset;
        rowptr[i] = rp;
        esrc[rp] = i;       // self-loop first
    }
    if (i == 0) rowptr[N_NODES] = E_TOT;
}

__global__ void scatter_edges(const int* __restrict__ ei, const int* __restrict__ rowptr,
                              const unsigned short* __restrict__ rank16,
                              int* __restrict__ esrc) {
    int nz = __syncthreads_or(ei[2 * threadIdx.x + 1]);
    int i = blockIdx.x * blockDim.x + threadIdx.x;
    if (2 * i >= N_EDGES) return;
    bool has2 = (2 * i + 1 < N_EDGES);
    int s0, d0, s1 = 0, d1 = 0;
    if (nz) {
        int2 sp = *(const int2*)(ei + 2 * i);
        int2 dp = *(const int2*)(ei + N_EDGES + 2 * i);
        s0 = sp.x; s1 = sp.y; d0 = dp.x; d1 = dp.y;
    } else {
        int4 sp = *(const int4*)(ei + 4 * i);
        int4 dp = *(const int4*)(ei + 2 * N_EDGES + 4 * i);
        s0 = sp.x; s1 = sp.z; d0 = dp.x; d1 = dp.z;
    }
    unsigned int rr = *(const unsigned int*)(rank16 + 2 * i);
    esrc[rowptr[d0] + 1 + (int)(rr & 0xffffu)] = s0;
    if (has2) esrc[rowptr[d1] + 1 + (int)(rr >> 16)] = s1;
}

// ---- fp32 -> bf16 bulk conversion (float4 in, 8B out) ----
__global__ void conv_bf16(const float* __restrict__ in, unsigned short* __restrict__ out,
                          int n4) {
    int i = blockIdx.x * 256 + threadIdx.x;
    if (i >= n4) return;
    float4 f = ((const float4*)in)[i];
    uint2 pk;
    pk.x = f2bf_pack2(f.x, f.y);
    pk.y = f2bf_pack2(f.z, f.w);
    *(uint2*)(out + 4 * i) = pk;
}

// ---- pack B pair into MFMA B-operand lane order ----
// Bp flat index = ((((m*4 + kt)*(N/16) + ct)*16 + n)*4 + quad)*8 + j
// element  = B_m[(kt*32 + quad*8 + j) * N + ct*16 + n]
template<int N>
__global__ void pack_B(const float* __restrict__ B0, const float* __restrict__ B1,
                       unsigned short* __restrict__ Bp) {
    int i = blockIdx.x * 256 + threadIdx.x;
    if (i >= 2 * 128 * N) return;
    int m   = i / (128 * N);
    int rem = i % (128 * N);
    int j    = rem & 7;
    int quad = (rem >> 3) & 3;
    int n    = (rem >> 5) & 15;
    int ctk  = rem >> 9;             // kt*(N/16) + ct
    int ct   = ctk % (N / 16);
    int kt   = ctk / (N / 16);
    int k    = kt * 32 + quad * 8 + j;
    int col  = ct * 16 + n;
    const float* B = m ? B1 : B0;
    Bp[i] = f2bf(B[k * N + col]);
}

// ---- MFMA GEMM pair: C0 = A@B0, C1 = A@B1 ; A[M,128] bf16, Bp packed bf16 ----
// N=128: 16 rows/block (grid 3125); wave: matrix = w>>1, col half = w&1.
// N=64 : 32 rows/block (grid 1563); wave: matrix = w>>1, row half = w&1.
template<int N>
__global__ __launch_bounds__(256)
void gemm_mfma(const unsigned short* __restrict__ Abf,
               const unsigned short* __restrict__ Bp,
               float* __restrict__ C0, float* __restrict__ C1, int M) {
    int w = threadIdx.x >> 6, lane = threadIdx.x & 63;
    int quad = lane >> 4, l16 = lane & 15;
    int matrix, row0, cb;
    if (N == 128) { matrix = w >> 1; row0 = blockIdx.x * 16;                cb = (w & 1) * 64; }
    else          { matrix = w >> 1; row0 = blockIdx.x * 32 + (w & 1) * 16; cb = 0; }
    float* C = matrix ? C1 : C0;
    const unsigned short* Bm = Bp + matrix * 128 * N;
    f32x4 acc[4];
    #pragma unroll
    for (int t = 0; t < 4; ++t) acc[t] = (f32x4){0.f, 0.f, 0.f, 0.f};
    int arow = row0 + l16;
    bool aok = arow < M;
    const short* Ap = (const short*)Abf + (size_t)arow * 128 + quad * 8;
    #pragma unroll
    for (int kt = 0; kt < 4; ++kt) {
        short8 a = (short8)0;
        if (aok) a = *(const short8*)(Ap + kt * 32);
        #pragma unroll
        for (int t = 0; t < 4; ++t) {
            int ct = (cb >> 4) + t;
            const short* bp = (const short*)Bm + (((kt * (N / 16) + ct) * 16 + l16) * 4 + quad) * 8;
            short8 b = *(const short8*)bp;
            acc[t] = __builtin_amdgcn_mfma_f32_16x16x32_bf16(a, b, acc[t], 0, 0, 0);
        }
    }
    // D: col = cb + t*16 + l16, row = row0 + quad*4 + r
    #pragma unroll
    for (int t = 0; t < 4; ++t) {
        int col = cb + t * 16 + l16;
        #pragma unroll
        for (int r = 0; r < 4; ++r) {
            int row = row0 + quad * 4 + r;
            if (row < M) C[(size_t)row * N + col] = acc[t][r];
        }
    }
}

// ---------------- Layer 1 (H=8, C=16) ----------------
// Node per wave; wave = 4 edge-slots x 16 lanes; lane holds 8 channels.
// Output h written as bf16 (feeds the layer-2 MFMA GEMM directly).
__global__ __launch_bounds__(256)
void node_fused1(const int* __restrict__ rowptr, const int* __restrict__ esrc,
                 const float* __restrict__ xl, const float* __restrict__ xr,
                 const float* __restrict__ att, const float* __restrict__ b1,
                 unsigned short* __restrict__ hbf) {
    int wave = threadIdx.x >> 6;
    int lane = threadIdx.x & 63;
    int n = blockIdx.x * 4 + wave;            // grid = 12500 exact
    int slot = lane >> 4;                     // 0..3
    int l = lane & 15;                        // channels 8l..8l+7
    int beg = rowptr[n], end = rowptr[n + 1];
    const float* xrp = xr + (size_t)n * 128 + 8 * l;
    float4 xra = *(const float4*)(xrp);
    float4 xrb = *(const float4*)(xrp + 4);
    float4 ata = *(const float4*)(att + 8 * l);
    float4 atb = *(const float4*)(att + 8 * l + 4);
    float den = 0.0f;
    float4 aa = {0, 0, 0, 0}, ab = {0, 0, 0, 0};

    auto body = [&](int k) {
        int s = esrc[k];
        const float* xp = xl + (size_t)s * 128 + 8 * l;
        float4 xa = *(const float4*)(xp);
        float4 xb = *(const float4*)(xp + 4);
        float v = ata.x * lrelu(xa.x + xra.x) + ata.y * lrelu(xa.y + xra.y)
                + ata.z * lrelu(xa.z + xra.z) + ata.w * lrelu(xa.w + xra.w)
                + atb.x * lrelu(xb.x + xrb.x) + atb.y * lrelu(xb.y + xrb.y)
                + atb.z * lrelu(xb.z + xrb.z) + atb.w * lrelu(xb.w + xrb.w);
        v += __shfl_xor(v, 1);                // combine the head's two lanes
        float p = __expf(v);
        den += p;
        aa.x += p * xa.x; aa.y += p * xa.y; aa.z += p * xa.z; aa.w += p * xa.w;
        ab.x += p * xb.x; ab.y += p * xb.y; ab.z += p * xb.z; ab.w += p * xb.w;
    };
    int k = beg + slot;
    for (; k + 4 < end; k += 8) { body(k); body(k + 4); }
    if (k < end) body(k);

    #pragma unroll
    for (int off = 16; off < 64; off <<= 1) {
        aa.x += __shfl_xor(aa.x, off); aa.y += __shfl_xor(aa.y, off);
        aa.z += __shfl_xor(aa.z, off); aa.w += __shfl_xor(aa.w, off);
        ab.x += __shfl_xor(ab.x, off); ab.y += __shfl_xor(ab.y, off);
        ab.z += __shfl_xor(ab.z, off); ab.w += __shfl_xor(ab.w, off);
        den   += __shfl_xor(den, off);
    }
    if (slot == 0) {
        float inv = 1.0f / (den + SM_EPS);
        float4 b4a = *(const float4*)(b1 + 8 * l);
        float4 b4b = *(const float4*)(b1 + 8 * l + 4);
        float oa0 = fmaxf(aa.x * inv + b4a.x, 0.0f);
        float oa1 = fmaxf(aa.y * inv + b4a.y, 0.0f);
        float oa2 = fmaxf(aa.z * inv + b4a.z, 0.0f);
        float oa3 = fmaxf(aa.w * inv + b4a.w, 0.0f);
        float ob0 = fmaxf(ab.x * inv + b4b.x, 0.0f);
        float ob1 = fmaxf(ab.y * inv + b4b.y, 0.0f);
        float ob2 = fmaxf(ab.z * inv + b4b.z, 0.0f);
        float ob3 = fmaxf(ab.w * inv + b4b.w, 0.0f);
        uint4 pk;
        pk.x = f2bf_pack2(oa0, oa1);
        pk.y = f2bf_pack2(oa2, oa3);
        pk.z = f2bf_pack2(ob0, ob1);
        pk.w = f2bf_pack2(ob2, ob3);
        *(uint4*)(hbf + (size_t)n * 128 + 8 * l) = pk;
    }
}

// ---------------- Layer 2 (H=1, C=64) ----------------
__global__ __launch_bounds__(256)
void node_fused2(const int* __restrict__ rowptr, const int* __restrict__ esrc,
                 const float* __restrict__ xl, const float* __restrict__ xr,
                 const float* __restrict__ att, const float* __restrict__ b2v,
                 float* __restrict__ out_emb) {
    int wave = threadIdx.x >> 6;
    int lane = threadIdx.x & 63;
    int n = blockIdx.x * 4 + wave;
    int slot = lane >> 3;                     // 0..7
    int l = lane & 7;                         // channels 8l..8l+7
    int beg = rowptr[n], end = rowptr[n + 1];
    const float* xrp = xr + (size_t)n * 64 + 8 * l;
    float4 xra = *(const float4*)(xrp);
    float4 xrb = *(const float4*)(xrp + 4);
    float4 ata = *(const float4*)(att + 8 * l);
    float4 atb = *(const float4*)(att + 8 * l + 4);
    float den = 0.0f;
    float4 aa = {0, 0, 0, 0}, ab = {0, 0, 0, 0};

    auto body = [&](int k) {
        int s = esrc[k];
        const float* xp = xl + (size_t)s * 64 + 8 * l;
        float4 xa = *(const float4*)(xp);
        float4 xb = *(const float4*)(xp + 4);
        float v = ata.x * lrelu(xa.x + xra.x) + ata.y * lrelu(xa.y + xra.y)
                + ata.z * lrelu(xa.z + xra.z) + ata.w * lrelu(xa.w + xra.w)
                + atb.x * lrelu(xb.x + xrb.x) + atb.y * lrelu(xb.y + xrb.y)
                + atb.z * lrelu(xb.z + xrb.z) + atb.w * lrelu(xb.w + xrb.w);
        v += __shfl_xor(v, 1);
        v += __shfl_xor(v, 2);
        v += __shfl_xor(v, 4);
        float p = __expf(v);
        den += p;
        aa.x += p * xa.x; aa.y += p * xa.y; aa.z += p * xa.z; aa.w += p * xa.w;
        ab.x += p * xb.x; ab.y += p * xb.y; ab.z += p * xb.z; ab.w += p * xb.w;
    };
    int k = beg + slot;
    for (; k + 8 < end; k += 16) { body(k); body(k + 8); }
    if (k < end) body(k);

    #pragma unroll
    for (int off = 8; off < 64; off <<= 1) {
        aa.x += __shfl_xor(aa.x, off); aa.y += __shfl_xor(aa.y, off);
        aa.z += __shfl_xor(aa.z, off); aa.w += __shfl_xor(aa.w, off);
        ab.x += __shfl_xor(ab.x, off); ab.y += __shfl_xor(ab.y, off);
        ab.z += __shfl_xor(ab.z, off); ab.w += __shfl_xor(ab.w, off);
        den   += __shfl_xor(den, off);
    }
    if (slot == 0) {
        float inv = 1.0f / (den + SM_EPS);
        float4 b4a = *(const float4*)(b2v + 8 * l);
        float4 b4b = *(const float4*)(b2v + 8 * l + 4);
        float4 ea, eb;
        ea.x = aa.x * inv + b4a.x; ea.y = aa.y * inv + b4a.y;
        ea.z = aa.z * inv + b4a.z; ea.w = aa.w * inv + b4a.w;
        eb.x = ab.x * inv + b4b.x; eb.y = ab.y * inv + b4b.y;
        eb.z = ab.z * inv + b4b.z; eb.w = ab.w * inv + b4b.w;
        float* op = out_emb + (size_t)n * 64 + 8 * l;
        *(float4*)(op)     = ea;
        *(float4*)(op + 4) = eb;
    }
}

// ---------------- Classifier: LDS-tiled ----------------
#define CLS_NODES 32
__global__ __launch_bounds__(256)
void classifier(const float* __restrict__ emb, const float* __restrict__ Wc1,
                const float* __restrict__ bc1, const float* __restrict__ Wc2,
                const float* __restrict__ bc2, float* __restrict__ out_logits) {
    __shared__ float w1[64 * 128];            // 32 KB
    __shared__ float eS[CLS_NODES][64];       // 8 KB
    __shared__ float tS[CLS_NODES][132];      // pad 132 breaks phase-C conflicts
    int t = threadIdx.x;
    int n0 = blockIdx.x * CLS_NODES;
    for (int i = t; i < 64 * 128 / 4; i += 256)
        ((float4*)w1)[i] = ((const float4*)Wc1)[i];
    for (int i = t; i < CLS_NODES * 64 / 4; i += 256) {
        size_t off = (size_t)n0 * 64 + i * 4;
        float4 v = {0, 0, 0, 0};
        if (off + 3 < (size_t)N_NODES * 64) v = *(const float4*)(emb + off);
        ((float4*)eS)[i] = v;
    }
    __syncthreads();
    int jj = t & 127, half = t >> 7;
    for (int nn = half; nn < CLS_NODES; nn += 2) {
        float a0 = 0, a1 = 0, a2 = 0, a3 = 0;
        #pragma unroll
        for (int k = 0; k < 64; k += 4) {
            a0 += eS[nn][k]     * w1[(k)     * 128 + jj];
            a1 += eS[nn][k + 1] * w1[(k + 1) * 128 + jj];
            a2 += eS[nn][k + 2] * w1[(k + 2) * 128 + jj];
            a3 += eS[nn][k + 3] * w1[(k + 3) * 128 + jj];
        }
        tS[nn][jj] = fmaxf(bc1[jj] + (a0 + a1) + (a2 + a3), 0.0f);
    }
    __syncthreads();
    int node = t >> 3, seg = t & 7;
    float v0 = 0, v1 = 0;
    #pragma unroll
    for (int c = 0; c < 16; ++c) {
        float tv = tS[node][seg * 16 + c];
        v0 += tv * Wc2[2 * (seg * 16 + c)];
        v1 += tv * Wc2[2 * (seg * 16 + c) + 1];
    }
    v0 += __shfl_xor(v0, 1); v1 += __shfl_xor(v1, 1);
    v0 += __shfl_xor(v0, 2); v1 += __shfl_xor(v1, 2);
    v0 += __shfl_xor(v0, 4); v1 += __shfl_xor(v1, 4);
    int n = n0 + node;
    if (seg == 0 && n < N_NODES) {
        out_logits[(size_t)n * 2 + 0] = v0 + bc2[0];
        out_logits[(size_t)n * 2 + 1] = v1 + bc2[1];
    }
}

extern "C" void kernel_launch(void* const* d_in, const int* in_sizes, int n_in,
                              void* d_out, int out_size, void* d_ws, size_t ws_size,
                              hipStream_t stream) {
    const float* x    = (const float*)d_in[0];
    const int*   ei   = (const int*)d_in[1];
    const float* Wl1  = (const float*)d_in[3];
    const float* Wr1  = (const float*)d_in[4];
    const float* att1 = (const float*)d_in[5];
    const float* b1   = (const float*)d_in[6];
    const float* Wl2  = (const float*)d_in[7];
    const float* Wr2  = (const float*)d_in[8];
    const float* att2 = (const float*)d_in[9];
    const float* b2   = (const float*)d_in[10];
    const float* Wc1  = (const float*)d_in[15];
    const float* bc1  = (const float*)d_in[16];
    const float* Wc2  = (const float*)d_in[17];
    const float* bc2  = (const float*)d_in[18];

    float* ws = (float*)d_ws;
    int* deg    = (int*)ws;                        //      0 .. 50000 (zeroed by memset)
    int* rowptr = deg + 50000;                     //  50000 .. 100016
    int* esrc   = rowptr + 50016;                  // 100016 .. 950016
    int* bsum   = esrc + 850000;                   // 950016 .. 950272
    unsigned short* rank16 = (unsigned short*)(bsum + 256);  // 400000 words
    float* xl1  = ws + 1400448;                    // 6.40M (layer2 xl2 in first 3.2M)
    float* xr1  = ws + 7800448;                    // 6.40M (layer2 xr2)
    unsigned short* xbf = (unsigned short*)(ws + 14200448);  // 6.4M bf16 = 3.2M words
    unsigned short* hbf = (unsigned short*)(ws + 17400448);  // 6.4M bf16 = 3.2M words
    unsigned short* Bp1 = (unsigned short*)(ws + 20600448);  // 32768 bf16 = 16384 words
    unsigned short* Bp2 = (unsigned short*)(ws + 20616832);  // 16384 bf16 =  8192 words
    // total ≈ 20.63M words ≈ 82.5 MB

    float* out_emb    = (float*)d_out;
    float* out_logits = out_emb + (size_t)N_NODES * 64;

    // ---- conversions / packing (input-only deps) ----
    conv_bf16<<<6250, 256, 0, stream>>>(x, xbf, N_NODES * 128 / 4);
    pack_B<128><<<128, 256, 0, stream>>>(Wl1, Wr1, Bp1);
    pack_B<64><<<64, 256, 0, stream>>>(Wl2, Wr2, Bp2);

    // ---- CSR build ----
    hipMemsetAsync(deg, 0, 50000 * sizeof(int), stream);
    count_deg<<<1563, 256, 0, stream>>>(ei, deg, rank16);
    scan_local<<<SCAN_B, 256, 0, stream>>>(deg, rowptr, bsum);
    scan_add<<<SCAN_B, 256, 0, stream>>>(rowptr, bsum, esrc);
    scatter_edges<<<1563, 256, 0, stream>>>(ei, rowptr, rank16, esrc);

    // ---- layer 1 ----
    gemm_mfma<128><<<3125, 256, 0, stream>>>(xbf, Bp1, xl1, xr1, N_NODES);
    node_fused1<<<12500, 256, 0, stream>>>(rowptr, esrc, xl1, xr1, att1, b1, hbf);

    // ---- layer 2 ----
    gemm_mfma<64><<<1563, 256, 0, stream>>>(hbf, Bp2, xl1, xr1, N_NODES);
    node_fused2<<<12500, 256, 0, stream>>>(rowptr, esrc, xl1, xr1, att2, b2, out_emb);

    // ---- classifier ----
    classifier<<<1563, 256, 0, stream>>>(out_emb, Wc1, bc1, Wc2, bc2, out_logits);
}

// Round 14
// 338.383 us; speedup vs baseline: 1.2442x; 1.0656x over previous
//
#include <hip/hip_runtime.h>
#include <hip/hip_bf16.h>
#include <cfloat>

#define N_NODES 50000
#define N_EDGES 800000
#define E_TOT   850000   /* edges + self-loops */
#define NEG_SLOPE 0.2f
#define SM_EPS 1e-16f
#define SCAN_B 196       /* ceil(50000/256) */

typedef __attribute__((ext_vector_type(8))) short short8;
typedef __attribute__((ext_vector_type(4))) float f32x4;

__device__ __forceinline__ float lrelu(float v) { return v > 0.0f ? v : NEG_SLOPE * v; }

// fp32 -> bf16 (RNE) pack / unpack helpers
__device__ __forceinline__ unsigned f2bf_pack2(float a, float b) {
    unsigned ua = __float_as_uint(a);
    ua += 0x7fff + ((ua >> 16) & 1);
    unsigned ub = __float_as_uint(b);
    ub += 0x7fff + ((ub >> 16) & 1);
    return (ua >> 16) | (ub & 0xffff0000u);
}
__device__ __forceinline__ unsigned short f2bf(float a) {
    unsigned ua = __float_as_uint(a);
    ua += 0x7fff + ((ua >> 16) & 1);
    return (unsigned short)(ua >> 16);
}
__device__ __forceinline__ float bf_lo(unsigned u) { return __uint_as_float(u << 16); }
__device__ __forceinline__ float bf_hi(unsigned u) { return __uint_as_float(u & 0xffff0000u); }

// ---- CSR build -------------------------------------------------------------
__global__ void count_deg(const int* __restrict__ ei, int* __restrict__ deg,
                          unsigned short* __restrict__ rank16) {
    int nz = __syncthreads_or(ei[2 * threadIdx.x + 1]);   // 0 => int64 layout
    int i = blockIdx.x * blockDim.x + threadIdx.x;        // edge-pair index
    if (2 * i >= N_EDGES) return;
    bool has2 = (2 * i + 1 < N_EDGES);
    int d0, d1 = 0;
    if (nz) {
        int2 dp = *(const int2*)(ei + N_EDGES + 2 * i);
        d0 = dp.x; d1 = dp.y;
    } else {
        int4 dp = *(const int4*)(ei + 2 * N_EDGES + 4 * i);
        d0 = dp.x; d1 = dp.z;
    }
    unsigned short r0 = (unsigned short)atomicAdd(&deg[d0], 1);
    unsigned short r1 = 0;
    if (has2) r1 = (unsigned short)atomicAdd(&deg[d1], 1);
    *(unsigned int*)(rank16 + 2 * i) = (unsigned int)r0 | ((unsigned int)r1 << 16);
}

__global__ void scan_local(const int* __restrict__ deg, int* __restrict__ rowptr,
                           int* __restrict__ bsum) {
    __shared__ int sh[256];
    int b = blockIdx.x, t = threadIdx.x, i = b * 256 + t;
    int v = (i < N_NODES) ? deg[i] + 1 : 0;
    sh[t] = v;
    __syncthreads();
    int val = v;
    for (int off = 1; off < 256; off <<= 1) {
        int add = (t >= off) ? sh[t - off] : 0;
        __syncthreads();
        val += add; sh[t] = val;
        __syncthreads();
    }
    if (i < N_NODES) rowptr[i] = val - v;
    if (t == 255) bsum[b] = val;
}

__global__ void scan_add(int* __restrict__ rowptr, const int* __restrict__ bsum,
                         int* __restrict__ esrc) {
    __shared__ int sh[256];
    int b = blockIdx.x, t = threadIdx.x;
    sh[t] = (t < b && t < SCAN_B) ? bsum[t] : 0;
    __syncthreads();
    #pragma unroll
    for (int off = 128; off; off >>= 1) {
        if (t < off) sh[t] += sh[t + off];
        __syncthreads();
    }
    int offset = sh[0];
    int i = b * 256 + t;
    if (i < N_NODES) {
        int rp = rowptr[i] + offset;
        rowptr[i] = rp;
        esrc[rp] = i;       // self-loop first
    }
    if (i == 0) rowptr[N_NODES] = E_TOT;
}

__global__ void scatter_edges(const int* __restrict__ ei, const int* __restrict__ rowptr,
                              const unsigned short* __restrict__ rank16,
                              int* __restrict__ esrc) {
    int nz = __syncthreads_or(ei[2 * threadIdx.x + 1]);
    int i = blockIdx.x * blockDim.x + threadIdx.x;
    if (2 * i >= N_EDGES) return;
    bool has2 = (2 * i + 1 < N_EDGES);
    int s0, d0, s1 = 0, d1 = 0;
    if (nz) {
        int2 sp = *(const int2*)(ei + 2 * i);
        int2 dp = *(const int2*)(ei + N_EDGES + 2 * i);
        s0 = sp.x; s1 = sp.y; d0 = dp.x; d1 = dp.y;
    } else {
        int4 sp = *(const int4*)(ei + 4 * i);
        int4 dp = *(const int4*)(ei + 2 * N_EDGES + 4 * i);
        s0 = sp.x; s1 = sp.z; d0 = dp.x; d1 = dp.z;
    }
    unsigned int rr = *(const unsigned int*)(rank16 + 2 * i);
    esrc[rowptr[d0] + 1 + (int)(rr & 0xffffu)] = s0;
    if (has2) esrc[rowptr[d1] + 1 + (int)(rr >> 16)] = s1;
}

// ---- fp32 -> bf16 bulk conversion (float4 in, 8B out) ----
__global__ void conv_bf16(const float* __restrict__ in, unsigned short* __restrict__ out,
                          int n4) {
    int i = blockIdx.x * 256 + threadIdx.x;
    if (i >= n4) return;
    float4 f = ((const float4*)in)[i];
    uint2 pk;
    pk.x = f2bf_pack2(f.x, f.y);
    pk.y = f2bf_pack2(f.z, f.w);
    *(uint2*)(out + 4 * i) = pk;
}

// ---- pack B pair into MFMA B-operand lane order ----
template<int N>
__global__ void pack_B(const float* __restrict__ B0, const float* __restrict__ B1,
                       unsigned short* __restrict__ Bp) {
    int i = blockIdx.x * 256 + threadIdx.x;
    if (i >= 2 * 128 * N) return;
    int m   = i / (128 * N);
    int rem = i % (128 * N);
    int j    = rem & 7;
    int quad = (rem >> 3) & 3;
    int n    = (rem >> 5) & 15;
    int ctk  = rem >> 9;
    int ct   = ctk % (N / 16);
    int kt   = ctk / (N / 16);
    int k    = kt * 32 + quad * 8 + j;
    int col  = ct * 16 + n;
    const float* B = m ? B1 : B0;
    Bp[i] = f2bf(B[k * N + col]);
}

// ---- MFMA GEMM pair: C0bf = bf16(A@B0), C1 = A@B1 (fp32) ----
template<int N>
__global__ __launch_bounds__(256)
void gemm_mfma(const unsigned short* __restrict__ Abf,
               const unsigned short* __restrict__ Bp,
               unsigned short* __restrict__ C0bf, float* __restrict__ C1, int M) {
    int w = threadIdx.x >> 6, lane = threadIdx.x & 63;
    int quad = lane >> 4, l16 = lane & 15;
    int matrix, row0, cb;
    if (N == 128) { matrix = w >> 1; row0 = blockIdx.x * 16;                cb = (w & 1) * 64; }
    else          { matrix = w >> 1; row0 = blockIdx.x * 32 + (w & 1) * 16; cb = 0; }
    const unsigned short* Bm = Bp + matrix * 128 * N;
    f32x4 acc[4];
    #pragma unroll
    for (int t = 0; t < 4; ++t) acc[t] = (f32x4){0.f, 0.f, 0.f, 0.f};
    int arow = row0 + l16;
    bool aok = arow < M;
    const short* Ap = (const short*)Abf + (size_t)arow * 128 + quad * 8;
    #pragma unroll
    for (int kt = 0; kt < 4; ++kt) {
        short8 a = (short8)0;
        if (aok) a = *(const short8*)(Ap + kt * 32);
        #pragma unroll
        for (int t = 0; t < 4; ++t) {
            int ct = (cb >> 4) + t;
            const short* bp = (const short*)Bm + (((kt * (N / 16) + ct) * 16 + l16) * 4 + quad) * 8;
            short8 b = *(const short8*)bp;
            acc[t] = __builtin_amdgcn_mfma_f32_16x16x32_bf16(a, b, acc[t], 0, 0, 0);
        }
    }
    // D: col = cb + t*16 + l16, row = row0 + quad*4 + r
    #pragma unroll
    for (int t = 0; t < 4; ++t) {
        int col = cb + t * 16 + l16;
        #pragma unroll
        for (int r = 0; r < 4; ++r) {
            int row = row0 + quad * 4 + r;
            if (row < M) {
                if (matrix) C1[(size_t)row * N + col] = acc[t][r];
                else        C0bf[(size_t)row * N + col] = f2bf(acc[t][r]);
            }
        }
    }
}

// ---------------- Layer 1 (H=8, C=16) ----------------
// Node per wave; wave = 4 edge-slots x 16 lanes; lane holds 8 channels.
// xl gathered as bf16 (uint4 per edge-body); h written bf16.
__global__ __launch_bounds__(256)
void node_fused1(const int* __restrict__ rowptr, const int* __restrict__ esrc,
                 const unsigned short* __restrict__ xlbf, const float* __restrict__ xr,
                 const float* __restrict__ att, const float* __restrict__ b1,
                 unsigned short* __restrict__ hbf) {
    int wave = threadIdx.x >> 6;
    int lane = threadIdx.x & 63;
    int n = blockIdx.x * 4 + wave;            // grid = 12500 exact
    int slot = lane >> 4;                     // 0..3
    int l = lane & 15;                        // channels 8l..8l+7
    int beg = rowptr[n], end = rowptr[n + 1];
    const float* xrp = xr + (size_t)n * 128 + 8 * l;
    float4 xra = *(const float4*)(xrp);
    float4 xrb = *(const float4*)(xrp + 4);
    float4 ata = *(const float4*)(att + 8 * l);
    float4 atb = *(const float4*)(att + 8 * l + 4);
    float den = 0.0f;
    float4 aa = {0, 0, 0, 0}, ab = {0, 0, 0, 0};

    auto body = [&](int k) {
        int s = esrc[k];
        uint4 u = *(const uint4*)(xlbf + (size_t)s * 128 + 8 * l);
        float x0 = bf_lo(u.x), x1 = bf_hi(u.x);
        float x2 = bf_lo(u.y), x3 = bf_hi(u.y);
        float x4 = bf_lo(u.z), x5 = bf_hi(u.z);
        float x6 = bf_lo(u.w), x7 = bf_hi(u.w);
        float v = ata.x * lrelu(x0 + xra.x) + ata.y * lrelu(x1 + xra.y)
                + ata.z * lrelu(x2 + xra.z) + ata.w * lrelu(x3 + xra.w)
                + atb.x * lrelu(x4 + xrb.x) + atb.y * lrelu(x5 + xrb.y)
                + atb.z * lrelu(x6 + xrb.z) + atb.w * lrelu(x7 + xrb.w);
        v += __shfl_xor(v, 1);                // combine the head's two lanes
        float p = __expf(v);
        den += p;
        aa.x += p * x0; aa.y += p * x1; aa.z += p * x2; aa.w += p * x3;
        ab.x += p * x4; ab.y += p * x5; ab.z += p * x6; ab.w += p * x7;
    };
    int k = beg + slot;
    for (; k + 4 < end; k += 8) { body(k); body(k + 4); }
    if (k < end) body(k);

    #pragma unroll
    for (int off = 16; off < 64; off <<= 1) {
        aa.x += __shfl_xor(aa.x, off); aa.y += __shfl_xor(aa.y, off);
        aa.z += __shfl_xor(aa.z, off); aa.w += __shfl_xor(aa.w, off);
        ab.x += __shfl_xor(ab.x, off); ab.y += __shfl_xor(ab.y, off);
        ab.z += __shfl_xor(ab.z, off); ab.w += __shfl_xor(ab.w, off);
        den   += __shfl_xor(den, off);
    }
    if (slot == 0) {
        float inv = 1.0f / (den + SM_EPS);
        float4 b4a = *(const float4*)(b1 + 8 * l);
        float4 b4b = *(const float4*)(b1 + 8 * l + 4);
        float oa0 = fmaxf(aa.x * inv + b4a.x, 0.0f);
        float oa1 = fmaxf(aa.y * inv + b4a.y, 0.0f);
        float oa2 = fmaxf(aa.z * inv + b4a.z, 0.0f);
        float oa3 = fmaxf(aa.w * inv + b4a.w, 0.0f);
        float ob0 = fmaxf(ab.x * inv + b4b.x, 0.0f);
        float ob1 = fmaxf(ab.y * inv + b4b.y, 0.0f);
        float ob2 = fmaxf(ab.z * inv + b4b.z, 0.0f);
        float ob3 = fmaxf(ab.w * inv + b4b.w, 0.0f);
        uint4 pk;
        pk.x = f2bf_pack2(oa0, oa1);
        pk.y = f2bf_pack2(oa2, oa3);
        pk.z = f2bf_pack2(ob0, ob1);
        pk.w = f2bf_pack2(ob2, ob3);
        *(uint4*)(hbf + (size_t)n * 128 + 8 * l) = pk;
    }
}

// ---------------- Layer 2 (H=1, C=64) ----------------
// Node per wave; wave = 8 edge-slots x 8 lanes; lane holds 8 channels (bf16 gather).
__global__ __launch_bounds__(256)
void node_fused2(const int* __restrict__ rowptr, const int* __restrict__ esrc,
                 const unsigned short* __restrict__ xlbf, const float* __restrict__ xr,
                 const float* __restrict__ att, const float* __restrict__ b2v,
                 float* __restrict__ out_emb) {
    int wave = threadIdx.x >> 6;
    int lane = threadIdx.x & 63;
    int n = blockIdx.x * 4 + wave;
    int slot = lane >> 3;                     // 0..7
    int l = lane & 7;                         // channels 8l..8l+7
    int beg = rowptr[n], end = rowptr[n + 1];
    const float* xrp = xr + (size_t)n * 64 + 8 * l;
    float4 xra = *(const float4*)(xrp);
    float4 xrb = *(const float4*)(xrp + 4);
    float4 ata = *(const float4*)(att + 8 * l);
    float4 atb = *(const float4*)(att + 8 * l + 4);
    float den = 0.0f;
    float4 aa = {0, 0, 0, 0}, ab = {0, 0, 0, 0};

    auto body = [&](int k) {
        int s = esrc[k];
        uint4 u = *(const uint4*)(xlbf + (size_t)s * 64 + 8 * l);
        float x0 = bf_lo(u.x), x1 = bf_hi(u.x);
        float x2 = bf_lo(u.y), x3 = bf_hi(u.y);
        float x4 = bf_lo(u.z), x5 = bf_hi(u.z);
        float x6 = bf_lo(u.w), x7 = bf_hi(u.w);
        float v = ata.x * lrelu(x0 + xra.x) + ata.y * lrelu(x1 + xra.y)
                + ata.z * lrelu(x2 + xra.z) + ata.w * lrelu(x3 + xra.w)
                + atb.x * lrelu(x4 + xrb.x) + atb.y * lrelu(x5 + xrb.y)
                + atb.z * lrelu(x6 + xrb.z) + atb.w * lrelu(x7 + xrb.w);
        v += __shfl_xor(v, 1);
        v += __shfl_xor(v, 2);
        v += __shfl_xor(v, 4);
        float p = __expf(v);
        den += p;
        aa.x += p * x0; aa.y += p * x1; aa.z += p * x2; aa.w += p * x3;
        ab.x += p * x4; ab.y += p * x5; ab.z += p * x6; ab.w += p * x7;
    };
    int k = beg + slot;
    for (; k + 8 < end; k += 16) { body(k); body(k + 8); }
    if (k < end) body(k);

    #pragma unroll
    for (int off = 8; off < 64; off <<= 1) {
        aa.x += __shfl_xor(aa.x, off); aa.y += __shfl_xor(aa.y, off);
        aa.z += __shfl_xor(aa.z, off); aa.w += __shfl_xor(aa.w, off);
        ab.x += __shfl_xor(ab.x, off); ab.y += __shfl_xor(ab.y, off);
        ab.z += __shfl_xor(ab.z, off); ab.w += __shfl_xor(ab.w, off);
        den   += __shfl_xor(den, off);
    }
    if (slot == 0) {
        float inv = 1.0f / (den + SM_EPS);
        float4 b4a = *(const float4*)(b2v + 8 * l);
        float4 b4b = *(const float4*)(b2v + 8 * l + 4);
        float4 ea, eb;
        ea.x = aa.x * inv + b4a.x; ea.y = aa.y * inv + b4a.y;
        ea.z = aa.z * inv + b4a.z; ea.w = aa.w * inv + b4a.w;
        eb.x = ab.x * inv + b4b.x; eb.y = ab.y * inv + b4b.y;
        eb.z = ab.z * inv + b4b.z; eb.w = ab.w * inv + b4b.w;
        float* op = out_emb + (size_t)n * 64 + 8 * l;
        *(float4*)(op)     = ea;
        *(float4*)(op + 4) = eb;
    }
}

// ---------------- Classifier: LDS-tiled ----------------
#define CLS_NODES 32
__global__ __launch_bounds__(256)
void classifier(const float* __restrict__ emb, const float* __restrict__ Wc1,
                const float* __restrict__ bc1, const float* __restrict__ Wc2,
                const float* __restrict__ bc2, float* __restrict__ out_logits) {
    __shared__ float w1[64 * 128];            // 32 KB
    __shared__ float eS[CLS_NODES][64];       // 8 KB
    __shared__ float tS[CLS_NODES][132];      // pad 132 breaks phase-C conflicts
    int t = threadIdx.x;
    int n0 = blockIdx.x * CLS_NODES;
    for (int i = t; i < 64 * 128 / 4; i += 256)
        ((float4*)w1)[i] = ((const float4*)Wc1)[i];
    for (int i = t; i < CLS_NODES * 64 / 4; i += 256) {
        size_t off = (size_t)n0 * 64 + i * 4;
        float4 v = {0, 0, 0, 0};
        if (off + 3 < (size_t)N_NODES * 64) v = *(const float4*)(emb + off);
        ((float4*)eS)[i] = v;
    }
    __syncthreads();
    int jj = t & 127, half = t >> 7;
    for (int nn = half; nn < CLS_NODES; nn += 2) {
        float a0 = 0, a1 = 0, a2 = 0, a3 = 0;
        #pragma unroll
        for (int k = 0; k < 64; k += 4) {
            a0 += eS[nn][k]     * w1[(k)     * 128 + jj];
            a1 += eS[nn][k + 1] * w1[(k + 1) * 128 + jj];
            a2 += eS[nn][k + 2] * w1[(k + 2) * 128 + jj];
            a3 += eS[nn][k + 3] * w1[(k + 3) * 128 + jj];
        }
        tS[nn][jj] = fmaxf(bc1[jj] + (a0 + a1) + (a2 + a3), 0.0f);
    }
    __syncthreads();
    int node = t >> 3, seg = t & 7;
    float v0 = 0, v1 = 0;
    #pragma unroll
    for (int c = 0; c < 16; ++c) {
        float tv = tS[node][seg * 16 + c];
        v0 += tv * Wc2[2 * (seg * 16 + c)];
        v1 += tv * Wc2[2 * (seg * 16 + c) + 1];
    }
    v0 += __shfl_xor(v0, 1); v1 += __shfl_xor(v1, 1);
    v0 += __shfl_xor(v0, 2); v1 += __shfl_xor(v1, 2);
    v0 += __shfl_xor(v0, 4); v1 += __shfl_xor(v1, 4);
    int n = n0 + node;
    if (seg == 0 && n < N_NODES) {
        out_logits[(size_t)n * 2 + 0] = v0 + bc2[0];
        out_logits[(size_t)n * 2 + 1] = v1 + bc2[1];
    }
}

extern "C" void kernel_launch(void* const* d_in, const int* in_sizes, int n_in,
                              void* d_out, int out_size, void* d_ws, size_t ws_size,
                              hipStream_t stream) {
    const float* x    = (const float*)d_in[0];
    const int*   ei   = (const int*)d_in[1];
    const float* Wl1  = (const float*)d_in[3];
    const float* Wr1  = (const float*)d_in[4];
    const float* att1 = (const float*)d_in[5];
    const float* b1   = (const float*)d_in[6];
    const float* Wl2  = (const float*)d_in[7];
    const float* Wr2  = (const float*)d_in[8];
    const float* att2 = (const float*)d_in[9];
    const float* b2   = (const float*)d_in[10];
    const float* Wc1  = (const float*)d_in[15];
    const float* bc1  = (const float*)d_in[16];
    const float* Wc2  = (const float*)d_in[17];
    const float* bc2  = (const float*)d_in[18];

    float* ws = (float*)d_ws;
    int* deg    = (int*)ws;                        //      0 .. 50000 (zeroed by memset)
    int* rowptr = deg + 50000;                     //  50000 .. 100016
    int* esrc   = rowptr + 50016;                  // 100016 .. 950016
    int* bsum   = esrc + 850000;                   // 950016 .. 950272
    unsigned short* rank16 = (unsigned short*)(bsum + 256);  // 400000 words
    float* xr1          = ws + 1400448;                      // 6.4M words fp32 (layer2 xr2 in first 3.2M)
    unsigned short* xlbf = (unsigned short*)(ws + 7800448);  // 6.4M bf16 = 3.2M words (layer2 xl2 reuses)
    unsigned short* hbf  = (unsigned short*)(ws + 11000448); // 3.2M words
    unsigned short* xbf  = (unsigned short*)(ws + 14200448); // 3.2M words
    unsigned short* Bp1  = (unsigned short*)(ws + 17400448); // 16384 words
    unsigned short* Bp2  = (unsigned short*)(ws + 17416832); // 8192 words
    // total ≈ 17.43M words ≈ 70 MB

    float* out_emb    = (float*)d_out;
    float* out_logits = out_emb + (size_t)N_NODES * 64;

    // ---- conversions / packing (input-only deps) ----
    conv_bf16<<<6250, 256, 0, stream>>>(x, xbf, N_NODES * 128 / 4);
    pack_B<128><<<128, 256, 0, stream>>>(Wl1, Wr1, Bp1);
    pack_B<64><<<64, 256, 0, stream>>>(Wl2, Wr2, Bp2);

    // ---- CSR build ----
    hipMemsetAsync(deg, 0, 50000 * sizeof(int), stream);
    count_deg<<<1563, 256, 0, stream>>>(ei, deg, rank16);
    scan_local<<<SCAN_B, 256, 0, stream>>>(deg, rowptr, bsum);
    scan_add<<<SCAN_B, 256, 0, stream>>>(rowptr, bsum, esrc);
    scatter_edges<<<1563, 256, 0, stream>>>(ei, rowptr, rank16, esrc);

    // ---- layer 1 ----
    gemm_mfma<128><<<3125, 256, 0, stream>>>(xbf, Bp1, xlbf, xr1, N_NODES);
    node_fused1<<<12500, 256, 0, stream>>>(rowptr, esrc, xlbf, xr1, att1, b1, hbf);

    // ---- layer 2 ----
    gemm_mfma<64><<<1563, 256, 0, stream>>>(hbf, Bp2, xlbf, xr1, N_NODES);
    node_fused2<<<12500, 256, 0, stream>>>(rowptr, esrc, xlbf, xr1, att2, b2, out_emb);

    // ---- classifier ----
    classifier<<<1563, 256, 0, stream>>>(out_emb, Wc1, bc1, Wc2, bc2, out_logits);
}

// Round 15
// 338.177 us; speedup vs baseline: 1.2450x; 1.0006x over previous
//
#include <hip/hip_runtime.h>
#include <hip/hip_bf16.h>
#include <cfloat>

#define N_NODES 50000
#define N_EDGES 800000
#define E_TOT   850000   /* edges + self-loops */
#define NEG_SLOPE 0.2f
#define SM_EPS 1e-16f
#define SCAN_B 196       /* ceil(50000/256) */

typedef __attribute__((ext_vector_type(8))) short short8;
typedef __attribute__((ext_vector_type(4))) float f32x4;

__device__ __forceinline__ float lrelu(float v) { return v > 0.0f ? v : NEG_SLOPE * v; }

// fp32 -> bf16 (RNE) pack / unpack helpers
__device__ __forceinline__ unsigned f2bf_pack2(float a, float b) {
    unsigned ua = __float_as_uint(a);
    ua += 0x7fff + ((ua >> 16) & 1);
    unsigned ub = __float_as_uint(b);
    ub += 0x7fff + ((ub >> 16) & 1);
    return (ua >> 16) | (ub & 0xffff0000u);
}
__device__ __forceinline__ unsigned short f2bf(float a) {
    unsigned ua = __float_as_uint(a);
    ua += 0x7fff + ((ua >> 16) & 1);
    return (unsigned short)(ua >> 16);
}
__device__ __forceinline__ float bf_lo(unsigned u) { return __uint_as_float(u << 16); }
__device__ __forceinline__ float bf_hi(unsigned u) { return __uint_as_float(u & 0xffff0000u); }

// ---- prep: pack Bp1 (N=128) + Bp2 (N=64) into MFMA B lane order, zero deg+flags ----
__device__ __forceinline__ unsigned short pack_one(const float* __restrict__ B0,
                                                   const float* __restrict__ B1,
                                                   int i, int N) {
    int m   = i / (128 * N);
    int rem = i % (128 * N);
    int j    = rem & 7;
    int quad = (rem >> 3) & 3;
    int n    = (rem >> 5) & 15;
    int ctk  = rem >> 9;
    int ct   = ctk % (N / 16);
    int kt   = ctk / (N / 16);
    int k    = kt * 32 + quad * 8 + j;
    int col  = ct * 16 + n;
    const float* B = m ? B1 : B0;
    return f2bf(B[k * N + col]);
}

__global__ void prep(const float* __restrict__ Wl1, const float* __restrict__ Wr1,
                     const float* __restrict__ Wl2, const float* __restrict__ Wr2,
                     unsigned short* __restrict__ Bp1, unsigned short* __restrict__ Bp2,
                     int* __restrict__ deg, int* __restrict__ flags) {
    int i = blockIdx.x * 256 + threadIdx.x;
    if (i < 32768) {                       // Bp1: 2*128*128
        Bp1[i] = pack_one(Wl1, Wr1, i, 128);
    } else if (i < 49152) {                // Bp2: 2*128*64
        Bp2[i - 32768] = pack_one(Wl2, Wr2, i - 32768, 64);
    } else if (i < 99152) {
        deg[i - 49152] = 0;
    } else if (i < 99408) {
        flags[i - 99152] = 0;
    }
}

// ---- CSR build -------------------------------------------------------------
// One atomic pass: histogram + per-edge rank. rank16 written sequentially.
__global__ void count_deg(const int* __restrict__ ei, int* __restrict__ deg,
                          unsigned short* __restrict__ rank16) {
    int nz = __syncthreads_or(ei[2 * threadIdx.x + 1]);   // 0 => int64 layout
    int i = blockIdx.x * blockDim.x + threadIdx.x;        // edge-pair index
    if (2 * i >= N_EDGES) return;
    bool has2 = (2 * i + 1 < N_EDGES);
    int d0, d1 = 0;
    if (nz) {
        int2 dp = *(const int2*)(ei + N_EDGES + 2 * i);
        d0 = dp.x; d1 = dp.y;
    } else {
        int4 dp = *(const int4*)(ei + 2 * N_EDGES + 4 * i);
        d0 = dp.x; d1 = dp.z;
    }
    unsigned short r0 = (unsigned short)atomicAdd(&deg[d0], 1);
    unsigned short r1 = 0;
    if (has2) r1 = (unsigned short)atomicAdd(&deg[d1], 1);
    *(unsigned int*)(rank16 + 2 * i) = (unsigned int)r0 | ((unsigned int)r1 << 16);
}

// Fused exclusive scan (+1/node self-loop): local scan -> publish block sum with
// flag -> spin on earlier blocks' flags -> add offset, write rowptr + self-loop.
// All 196 blocks co-resident on 256 CUs => spin is deadlock-free.
__global__ void scan_fused(const int* __restrict__ deg, int* __restrict__ rowptr,
                           int* __restrict__ esrc, int* __restrict__ bsum,
                           int* __restrict__ flags) {
    __shared__ int sh[256];
    int b = blockIdx.x, t = threadIdx.x, i = b * 256 + t;
    int v = (i < N_NODES) ? deg[i] + 1 : 0;
    sh[t] = v;
    __syncthreads();
    int val = v;
    for (int off = 1; off < 256; off <<= 1) {
        int add = (t >= off) ? sh[t - off] : 0;
        __syncthreads();
        val += add; sh[t] = val;
        __syncthreads();
    }
    if (t == 255) {
        bsum[b] = val;                 // block-inclusive total
        __threadfence();
        atomicExch(&flags[b], 1);
    }
    // gather offsets of preceding blocks
    int contrib = 0;
    if (t < b) {
        while (atomicAdd(&flags[t], 0) == 0) {}
        contrib = atomicAdd(&bsum[t], 0);
    }
    __syncthreads();
    sh[t] = contrib;
    __syncthreads();
    #pragma unroll
    for (int off = 128; off; off >>= 1) {
        if (t < off) sh[t] += sh[t + off];
        __syncthreads();
    }
    int offset = sh[0];
    if (i < N_NODES) {
        int rp = (val - v) + offset;
        rowptr[i] = rp;
        esrc[rp] = i;       // self-loop first
    }
    if (i == 0) rowptr[N_NODES] = E_TOT;
}

// no atomics: position = rowptr[dst] + 1 + rank
__global__ void scatter_edges(const int* __restrict__ ei, const int* __restrict__ rowptr,
                              const unsigned short* __restrict__ rank16,
                              int* __restrict__ esrc) {
    int nz = __syncthreads_or(ei[2 * threadIdx.x + 1]);
    int i = blockIdx.x * blockDim.x + threadIdx.x;
    if (2 * i >= N_EDGES) return;
    bool has2 = (2 * i + 1 < N_EDGES);
    int s0, d0, s1 = 0, d1 = 0;
    if (nz) {
        int2 sp = *(const int2*)(ei + 2 * i);
        int2 dp = *(const int2*)(ei + N_EDGES + 2 * i);
        s0 = sp.x; s1 = sp.y; d0 = dp.x; d1 = dp.y;
    } else {
        int4 sp = *(const int4*)(ei + 4 * i);
        int4 dp = *(const int4*)(ei + 2 * N_EDGES + 4 * i);
        s0 = sp.x; s1 = sp.z; d0 = dp.x; d1 = dp.z;
    }
    unsigned int rr = *(const unsigned int*)(rank16 + 2 * i);
    esrc[rowptr[d0] + 1 + (int)(rr & 0xffffu)] = s0;
    if (has2) esrc[rowptr[d1] + 1 + (int)(rr >> 16)] = s1;
}

// ---- MFMA GEMM pair: C0bf = bf16(A@B0), C1 = A@B1 (fp32) ----
// AF32: A read as fp32 and converted in-register (layer 1); else A is bf16 (layer 2).
template<int N, bool AF32>
__global__ __launch_bounds__(256)
void gemm_mfma(const void* __restrict__ Aptr, const unsigned short* __restrict__ Bp,
               unsigned short* __restrict__ C0bf, float* __restrict__ C1, int M) {
    int w = threadIdx.x >> 6, lane = threadIdx.x & 63;
    int quad = lane >> 4, l16 = lane & 15;
    int matrix, row0, cb;
    if (N == 128) { matrix = w >> 1; row0 = blockIdx.x * 16;                cb = (w & 1) * 64; }
    else          { matrix = w >> 1; row0 = blockIdx.x * 32 + (w & 1) * 16; cb = 0; }
    const unsigned short* Bm = Bp + matrix * 128 * N;
    f32x4 acc[4];
    #pragma unroll
    for (int t = 0; t < 4; ++t) acc[t] = (f32x4){0.f, 0.f, 0.f, 0.f};
    int arow = row0 + l16;
    bool aok = arow < M;
    #pragma unroll
    for (int kt = 0; kt < 4; ++kt) {
        short8 a = (short8)0;
        if (aok) {
            if (AF32) {
                const float* Ap = (const float*)Aptr + (size_t)arow * 128 + quad * 8 + kt * 32;
                float4 f0 = *(const float4*)(Ap);
                float4 f1 = *(const float4*)(Ap + 4);
                union { uint4 u; short8 s; } cv;
                cv.u.x = f2bf_pack2(f0.x, f0.y);
                cv.u.y = f2bf_pack2(f0.z, f0.w);
                cv.u.z = f2bf_pack2(f1.x, f1.y);
                cv.u.w = f2bf_pack2(f1.z, f1.w);
                a = cv.s;
            } else {
                a = *(const short8*)((const short*)Aptr + (size_t)arow * 128 + quad * 8 + kt * 32);
            }
        }
        #pragma unroll
        for (int t = 0; t < 4; ++t) {
            int ct = (cb >> 4) + t;
            const short* bp = (const short*)Bm + (((kt * (N / 16) + ct) * 16 + l16) * 4 + quad) * 8;
            short8 b = *(const short8*)bp;
            acc[t] = __builtin_amdgcn_mfma_f32_16x16x32_bf16(a, b, acc[t], 0, 0, 0);
        }
    }
    // D: col = cb + t*16 + l16, row = row0 + quad*4 + r
    #pragma unroll
    for (int t = 0; t < 4; ++t) {
        int col = cb + t * 16 + l16;
        #pragma unroll
        for (int r = 0; r < 4; ++r) {
            int row = row0 + quad * 4 + r;
            if (row < M) {
                if (matrix) C1[(size_t)row * N + col] = acc[t][r];
                else        C0bf[(size_t)row * N + col] = f2bf(acc[t][r]);
            }
        }
    }
}

// ---------------- Layer 1 (H=8, C=16) ----------------
__global__ __launch_bounds__(256)
void node_fused1(const int* __restrict__ rowptr, const int* __restrict__ esrc,
                 const unsigned short* __restrict__ xlbf, const float* __restrict__ xr,
                 const float* __restrict__ att, const float* __restrict__ b1,
                 unsigned short* __restrict__ hbf) {
    int wave = threadIdx.x >> 6;
    int lane = threadIdx.x & 63;
    int n = blockIdx.x * 4 + wave;            // grid = 12500 exact
    int slot = lane >> 4;                     // 0..3
    int l = lane & 15;                        // channels 8l..8l+7
    int beg = rowptr[n], end = rowptr[n + 1];
    const float* xrp = xr + (size_t)n * 128 + 8 * l;
    float4 xra = *(const float4*)(xrp);
    float4 xrb = *(const float4*)(xrp + 4);
    float4 ata = *(const float4*)(att + 8 * l);
    float4 atb = *(const float4*)(att + 8 * l + 4);
    float den = 0.0f;
    float4 aa = {0, 0, 0, 0}, ab = {0, 0, 0, 0};

    auto body = [&](int k) {
        int s = esrc[k];
        uint4 u = *(const uint4*)(xlbf + (size_t)s * 128 + 8 * l);
        float x0 = bf_lo(u.x), x1 = bf_hi(u.x);
        float x2 = bf_lo(u.y), x3 = bf_hi(u.y);
        float x4 = bf_lo(u.z), x5 = bf_hi(u.z);
        float x6 = bf_lo(u.w), x7 = bf_hi(u.w);
        float v = ata.x * lrelu(x0 + xra.x) + ata.y * lrelu(x1 + xra.y)
                + ata.z * lrelu(x2 + xra.z) + ata.w * lrelu(x3 + xra.w)
                + atb.x * lrelu(x4 + xrb.x) + atb.y * lrelu(x5 + xrb.y)
                + atb.z * lrelu(x6 + xrb.z) + atb.w * lrelu(x7 + xrb.w);
        v += __shfl_xor(v, 1);                // combine the head's two lanes
        float p = __expf(v);
        den += p;
        aa.x += p * x0; aa.y += p * x1; aa.z += p * x2; aa.w += p * x3;
        ab.x += p * x4; ab.y += p * x5; ab.z += p * x6; ab.w += p * x7;
    };
    int k = beg + slot;
    for (; k + 4 < end; k += 8) { body(k); body(k + 4); }
    if (k < end) body(k);

    #pragma unroll
    for (int off = 16; off < 64; off <<= 1) {
        aa.x += __shfl_xor(aa.x, off); aa.y += __shfl_xor(aa.y, off);
        aa.z += __shfl_xor(aa.z, off); aa.w += __shfl_xor(aa.w, off);
        ab.x += __shfl_xor(ab.x, off); ab.y += __shfl_xor(ab.y, off);
        ab.z += __shfl_xor(ab.z, off); ab.w += __shfl_xor(ab.w, off);
        den   += __shfl_xor(den, off);
    }
    if (slot == 0) {
        float inv = 1.0f / (den + SM_EPS);
        float4 b4a = *(const float4*)(b1 + 8 * l);
        float4 b4b = *(const float4*)(b1 + 8 * l + 4);
        float oa0 = fmaxf(aa.x * inv + b4a.x, 0.0f);
        float oa1 = fmaxf(aa.y * inv + b4a.y, 0.0f);
        float oa2 = fmaxf(aa.z * inv + b4a.z, 0.0f);
        float oa3 = fmaxf(aa.w * inv + b4a.w, 0.0f);
        float ob0 = fmaxf(ab.x * inv + b4b.x, 0.0f);
        float ob1 = fmaxf(ab.y * inv + b4b.y, 0.0f);
        float ob2 = fmaxf(ab.z * inv + b4b.z, 0.0f);
        float ob3 = fmaxf(ab.w * inv + b4b.w, 0.0f);
        uint4 pk;
        pk.x = f2bf_pack2(oa0, oa1);
        pk.y = f2bf_pack2(oa2, oa3);
        pk.z = f2bf_pack2(ob0, ob1);
        pk.w = f2bf_pack2(ob2, ob3);
        *(uint4*)(hbf + (size_t)n * 128 + 8 * l) = pk;
    }
}

// ---------------- Layer 2 (H=1, C=64) ----------------
__global__ __launch_bounds__(256)
void node_fused2(const int* __restrict__ rowptr, const int* __restrict__ esrc,
                 const unsigned short* __restrict__ xlbf, const float* __restrict__ xr,
                 const float* __restrict__ att, const float* __restrict__ b2v,
                 float* __restrict__ out_emb) {
    int wave = threadIdx.x >> 6;
    int lane = threadIdx.x & 63;
    int n = blockIdx.x * 4 + wave;
    int slot = lane >> 3;                     // 0..7
    int l = lane & 7;                         // channels 8l..8l+7
    int beg = rowptr[n], end = rowptr[n + 1];
    const float* xrp = xr + (size_t)n * 64 + 8 * l;
    float4 xra = *(const float4*)(xrp);
    float4 xrb = *(const float4*)(xrp + 4);
    float4 ata = *(const float4*)(att + 8 * l);
    float4 atb = *(const float4*)(att + 8 * l + 4);
    float den = 0.0f;
    float4 aa = {0, 0, 0, 0}, ab = {0, 0, 0, 0};

    auto body = [&](int k) {
        int s = esrc[k];
        uint4 u = *(const uint4*)(xlbf + (size_t)s * 64 + 8 * l);
        float x0 = bf_lo(u.x), x1 = bf_hi(u.x);
        float x2 = bf_lo(u.y), x3 = bf_hi(u.y);
        float x4 = bf_lo(u.z), x5 = bf_hi(u.z);
        float x6 = bf_lo(u.w), x7 = bf_hi(u.w);
        float v = ata.x * lrelu(x0 + xra.x) + ata.y * lrelu(x1 + xra.y)
                + ata.z * lrelu(x2 + xra.z) + ata.w * lrelu(x3 + xra.w)
                + atb.x * lrelu(x4 + xrb.x) + atb.y * lrelu(x5 + xrb.y)
                + atb.z * lrelu(x6 + xrb.z) + atb.w * lrelu(x7 + xrb.w);
        v += __shfl_xor(v, 1);
        v += __shfl_xor(v, 2);
        v += __shfl_xor(v, 4);
        float p = __expf(v);
        den += p;
        aa.x += p * x0; aa.y += p * x1; aa.z += p * x2; aa.w += p * x3;
        ab.x += p * x4; ab.y += p * x5; ab.z += p * x6; ab.w += p * x7;
    };
    int k = beg + slot;
    for (; k + 8 < end; k += 16) { body(k); body(k + 8); }
    if (k < end) body(k);

    #pragma unroll
    for (int off = 8; off < 64; off <<= 1) {
        aa.x += __shfl_xor(aa.x, off); aa.y += __shfl_xor(aa.y, off);
        aa.z += __shfl_xor(aa.z, off); aa.w += __shfl_xor(aa.w, off);
        ab.x += __shfl_xor(ab.x, off); ab.y += __shfl_xor(ab.y, off);
        ab.z += __shfl_xor(ab.z, off); ab.w += __shfl_xor(ab.w, off);
        den   += __shfl_xor(den, off);
    }
    if (slot == 0) {
        float inv = 1.0f / (den + SM_EPS);
        float4 b4a = *(const float4*)(b2v + 8 * l);
        float4 b4b = *(const float4*)(b2v + 8 * l + 4);
        float4 ea, eb;
        ea.x = aa.x * inv + b4a.x; ea.y = aa.y * inv + b4a.y;
        ea.z = aa.z * inv + b4a.z; ea.w = aa.w * inv + b4a.w;
        eb.x = ab.x * inv + b4b.x; eb.y = ab.y * inv + b4b.y;
        eb.z = ab.z * inv + b4b.z; eb.w = ab.w * inv + b4b.w;
        float* op = out_emb + (size_t)n * 64 + 8 * l;
        *(float4*)(op)     = ea;
        *(float4*)(op + 4) = eb;
    }
}

// ---------------- Classifier: LDS-tiled ----------------
#define CLS_NODES 32
__global__ __launch_bounds__(256)
void classifier(const float* __restrict__ emb, const float* __restrict__ Wc1,
                const float* __restrict__ bc1, const float* __restrict__ Wc2,
                const float* __restrict__ bc2, float* __restrict__ out_logits) {
    __shared__ float w1[64 * 128];            // 32 KB
    __shared__ float eS[CLS_NODES][64];       // 8 KB
    __shared__ float tS[CLS_NODES][132];      // pad 132 breaks phase-C conflicts
    int t = threadIdx.x;
    int n0 = blockIdx.x * CLS_NODES;
    for (int i = t; i < 64 * 128 / 4; i += 256)
        ((float4*)w1)[i] = ((const float4*)Wc1)[i];
    for (int i = t; i < CLS_NODES * 64 / 4; i += 256) {
        size_t off = (size_t)n0 * 64 + i * 4;
        float4 v = {0, 0, 0, 0};
        if (off + 3 < (size_t)N_NODES * 64) v = *(const float4*)(emb + off);
        ((float4*)eS)[i] = v;
    }
    __syncthreads();
    int jj = t & 127, half = t >> 7;
    for (int nn = half; nn < CLS_NODES; nn += 2) {
        float a0 = 0, a1 = 0, a2 = 0, a3 = 0;
        #pragma unroll
        for (int k = 0; k < 64; k += 4) {
            a0 += eS[nn][k]     * w1[(k)     * 128 + jj];
            a1 += eS[nn][k + 1] * w1[(k + 1) * 128 + jj];
            a2 += eS[nn][k + 2] * w1[(k + 2) * 128 + jj];
            a3 += eS[nn][k + 3] * w1[(k + 3) * 128 + jj];
        }
        tS[nn][jj] = fmaxf(bc1[jj] + (a0 + a1) + (a2 + a3), 0.0f);
    }
    __syncthreads();
    int node = t >> 3, seg = t & 7;
    float v0 = 0, v1 = 0;
    #pragma unroll
    for (int c = 0; c < 16; ++c) {
        float tv = tS[node][seg * 16 + c];
        v0 += tv * Wc2[2 * (seg * 16 + c)];
        v1 += tv * Wc2[2 * (seg * 16 + c) + 1];
    }
    v0 += __shfl_xor(v0, 1); v1 += __shfl_xor(v1, 1);
    v0 += __shfl_xor(v0, 2); v1 += __shfl_xor(v1, 2);
    v0 += __shfl_xor(v0, 4); v1 += __shfl_xor(v1, 4);
    int n = n0 + node;
    if (seg == 0 && n < N_NODES) {
        out_logits[(size_t)n * 2 + 0] = v0 + bc2[0];
        out_logits[(size_t)n * 2 + 1] = v1 + bc2[1];
    }
}

extern "C" void kernel_launch(void* const* d_in, const int* in_sizes, int n_in,
                              void* d_out, int out_size, void* d_ws, size_t ws_size,
                              hipStream_t stream) {
    const float* x    = (const float*)d_in[0];
    const int*   ei   = (const int*)d_in[1];
    const float* Wl1  = (const float*)d_in[3];
    const float* Wr1  = (const float*)d_in[4];
    const float* att1 = (const float*)d_in[5];
    const float* b1   = (const float*)d_in[6];
    const float* Wl2  = (const float*)d_in[7];
    const float* Wr2  = (const float*)d_in[8];
    const float* att2 = (const float*)d_in[9];
    const float* b2   = (const float*)d_in[10];
    const float* Wc1  = (const float*)d_in[15];
    const float* bc1  = (const float*)d_in[16];
    const float* Wc2  = (const float*)d_in[17];
    const float* bc2  = (const float*)d_in[18];

    float* ws = (float*)d_ws;
    int* deg    = (int*)ws;                        //      0 .. 50000
    int* rowptr = deg + 50000;                     //  50000 .. 100016
    int* esrc   = rowptr + 50016;                  // 100016 .. 950016
    int* bsum   = esrc + 850000;                   // 950016 .. 950272
    int* flags  = bsum + 256;                      // 950272 .. 950528
    unsigned short* rank16 = (unsigned short*)(flags + 256);   // 400000 words
    float* xr1          = ws + 1400448;                        // 6.4M words (layer2 xr2 in first 3.2M)
    unsigned short* xlbf = (unsigned short*)(ws + 7800448);    // 3.2M words (layer2 xl2 reuses)
    unsigned short* hbf  = (unsigned short*)(ws + 11000448);   // 3.2M words
    unsigned short* Bp1  = (unsigned short*)(ws + 14200448);   // 16384 words
    unsigned short* Bp2  = (unsigned short*)(ws + 14216832);   // 8192 words
    // total ≈ 14.2M words ≈ 57 MB

    float* out_emb    = (float*)d_out;
    float* out_logits = out_emb + (size_t)N_NODES * 64;

    // ---- prep: pack weights, zero deg + flags (1 kernel) ----
    prep<<<389, 256, 0, stream>>>(Wl1, Wr1, Wl2, Wr2, Bp1, Bp2, deg, flags);

    // ---- CSR build (3 kernels) ----
    count_deg<<<1563, 256, 0, stream>>>(ei, deg, rank16);
    scan_fused<<<SCAN_B, 256, 0, stream>>>(deg, rowptr, esrc, bsum, flags);
    scatter_edges<<<1563, 256, 0, stream>>>(ei, rowptr, rank16, esrc);

    // ---- layer 1 ----
    gemm_mfma<128, true><<<3125, 256, 0, stream>>>(x, Bp1, xlbf, xr1, N_NODES);
    node_fused1<<<12500, 256, 0, stream>>>(rowptr, esrc, xlbf, xr1, att1, b1, hbf);

    // ---- layer 2 ----
    gemm_mfma<64, false><<<1563, 256, 0, stream>>>(hbf, Bp2, xlbf, xr1, N_NODES);
    node_fused2<<<12500, 256, 0, stream>>>(rowptr, esrc, xlbf, xr1, att2, b2, out_emb);

    // ---- classifier ----
    classifier<<<1563, 256, 0, stream>>>(out_emb, Wc1, bc1, Wc2, bc2, out_logits);
}

// Round 16
// 326.013 us; speedup vs baseline: 1.2914x; 1.0373x over previous
//
#include <hip/hip_runtime.h>
#include <hip/hip_bf16.h>
#include <cfloat>

#define N_NODES 50000
#define N_EDGES 800000
#define E_TOT   850000   /* edges + self-loops */
#define NEG_SLOPE 0.2f
#define SM_EPS 1e-16f
#define SCAN_B 196       /* ceil(50000/256) */

typedef __attribute__((ext_vector_type(8))) short short8;
typedef __attribute__((ext_vector_type(4))) float f32x4;

__device__ __forceinline__ float lrelu(float v) { return v > 0.0f ? v : NEG_SLOPE * v; }

// fp32 -> bf16 (RNE) pack / unpack helpers
__device__ __forceinline__ unsigned f2bf_pack2(float a, float b) {
    unsigned ua = __float_as_uint(a);
    ua += 0x7fff + ((ua >> 16) & 1);
    unsigned ub = __float_as_uint(b);
    ub += 0x7fff + ((ub >> 16) & 1);
    return (ua >> 16) | (ub & 0xffff0000u);
}
__device__ __forceinline__ unsigned short f2bf(float a) {
    unsigned ua = __float_as_uint(a);
    ua += 0x7fff + ((ua >> 16) & 1);
    return (unsigned short)(ua >> 16);
}
__device__ __forceinline__ float bf_lo(unsigned u) { return __uint_as_float(u << 16); }
__device__ __forceinline__ float bf_hi(unsigned u) { return __uint_as_float(u & 0xffff0000u); }

// ---- prep: pack Bp1 (N=128) + Bp2 (N=64) into MFMA B lane order, zero deg+flags ----
__device__ __forceinline__ unsigned short pack_one(const float* __restrict__ B0,
                                                   const float* __restrict__ B1,
                                                   int i, int N) {
    int m   = i / (128 * N);
    int rem = i % (128 * N);
    int j    = rem & 7;
    int quad = (rem >> 3) & 3;
    int n    = (rem >> 5) & 15;
    int ctk  = rem >> 9;
    int ct   = ctk % (N / 16);
    int kt   = ctk / (N / 16);
    int k    = kt * 32 + quad * 8 + j;
    int col  = ct * 16 + n;
    const float* B = m ? B1 : B0;
    return f2bf(B[k * N + col]);
}

__global__ void prep(const float* __restrict__ Wl1, const float* __restrict__ Wr1,
                     const float* __restrict__ Wl2, const float* __restrict__ Wr2,
                     unsigned short* __restrict__ Bp1, unsigned short* __restrict__ Bp2,
                     int* __restrict__ deg, int* __restrict__ flags) {
    int i = blockIdx.x * 256 + threadIdx.x;
    if (i < 32768) {
        Bp1[i] = pack_one(Wl1, Wr1, i, 128);
    } else if (i < 49152) {
        Bp2[i - 32768] = pack_one(Wl2, Wr2, i - 32768, 64);
    } else if (i < 99152) {
        deg[i - 49152] = 0;
    } else if (i < 99408) {
        flags[i - 99152] = 0;
    }
}

// ---- GEMM wave body: one matrix half of layer-1 GEMM (N=128, A fp32 in-reg converted) ----
// 32 rows per sub-block; 4 waves: row half = w&1, col half = w>>1.
__device__ __forceinline__ void gemm128_half(int b, const float* __restrict__ x,
                                             const unsigned short* __restrict__ Bm,
                                             unsigned short* __restrict__ Cbf,
                                             float* __restrict__ Cf, int M) {
    int w = threadIdx.x >> 6, lane = threadIdx.x & 63;
    int quad = lane >> 4, l16 = lane & 15;
    int row0 = b * 32 + (w & 1) * 16;
    int cb   = (w >> 1) * 64;
    f32x4 acc[4];
    #pragma unroll
    for (int t = 0; t < 4; ++t) acc[t] = (f32x4){0.f, 0.f, 0.f, 0.f};
    int arow = row0 + l16;
    bool aok = arow < M;
    #pragma unroll
    for (int kt = 0; kt < 4; ++kt) {
        short8 a = (short8)0;
        if (aok) {
            const float* Ap = x + (size_t)arow * 128 + quad * 8 + kt * 32;
            float4 f0 = *(const float4*)(Ap);
            float4 f1 = *(const float4*)(Ap + 4);
            union { uint4 u; short8 s; } cv;
            cv.u.x = f2bf_pack2(f0.x, f0.y);
            cv.u.y = f2bf_pack2(f0.z, f0.w);
            cv.u.z = f2bf_pack2(f1.x, f1.y);
            cv.u.w = f2bf_pack2(f1.z, f1.w);
            a = cv.s;
        }
        #pragma unroll
        for (int t = 0; t < 4; ++t) {
            int ct = (cb >> 4) + t;
            const short* bp = (const short*)Bm + (((kt * 8 + ct) * 16 + l16) * 4 + quad) * 8;
            short8 bfr = *(const short8*)bp;
            acc[t] = __builtin_amdgcn_mfma_f32_16x16x32_bf16(a, bfr, acc[t], 0, 0, 0);
        }
    }
    #pragma unroll
    for (int t = 0; t < 4; ++t) {
        int col = cb + t * 16 + l16;
        #pragma unroll
        for (int r = 0; r < 4; ++r) {
            int row = row0 + quad * 4 + r;
            if (row < M) {
                if (Cbf) Cbf[(size_t)row * 128 + col] = f2bf(acc[t][r]);
                else     Cf[(size_t)row * 128 + col]  = acc[t][r];
            }
        }
    }
}

// ---- K2: count_deg (odd blocks) + gemm xl-half (even blocks), interleaved ----
__global__ __launch_bounds__(256)
void k_count_gemmxl(const int* __restrict__ ei, int* __restrict__ deg,
                    unsigned short* __restrict__ rank16,
                    const float* __restrict__ x, const unsigned short* __restrict__ Bp1,
                    unsigned short* __restrict__ xlbf, int M) {
    int sub = blockIdx.x >> 1;
    if (blockIdx.x & 1) {
        // count_deg: one atomic pass, rank recorded
        int nz = __syncthreads_or(ei[2 * threadIdx.x + 1]);   // 0 => int64 layout
        int i = sub * 256 + threadIdx.x;
        if (2 * i >= N_EDGES) return;
        bool has2 = (2 * i + 1 < N_EDGES);
        int d0, d1 = 0;
        if (nz) {
            int2 dp = *(const int2*)(ei + N_EDGES + 2 * i);
            d0 = dp.x; d1 = dp.y;
        } else {
            int4 dp = *(const int4*)(ei + 2 * N_EDGES + 4 * i);
            d0 = dp.x; d1 = dp.z;
        }
        unsigned short r0 = (unsigned short)atomicAdd(&deg[d0], 1);
        unsigned short r1 = 0;
        if (has2) r1 = (unsigned short)atomicAdd(&deg[d1], 1);
        *(unsigned int*)(rank16 + 2 * i) = (unsigned int)r0 | ((unsigned int)r1 << 16);
    } else {
        gemm128_half(sub, x, Bp1, xlbf, nullptr, M);
    }
}

// ---- scan (fused, single kernel; publish/spin over block sums) ----
__global__ void scan_fused(const int* __restrict__ deg, int* __restrict__ rowptr,
                           int* __restrict__ esrc, int* __restrict__ bsum,
                           int* __restrict__ flags) {
    __shared__ int sh[256];
    int b = blockIdx.x, t = threadIdx.x, i = b * 256 + t;
    int v = (i < N_NODES) ? deg[i] + 1 : 0;
    sh[t] = v;
    __syncthreads();
    int val = v;
    for (int off = 1; off < 256; off <<= 1) {
        int add = (t >= off) ? sh[t - off] : 0;
        __syncthreads();
        val += add; sh[t] = val;
        __syncthreads();
    }
    if (t == 255) {
        bsum[b] = val;
        __threadfence();
        atomicExch(&flags[b], 1);
    }
    int contrib = 0;
    if (t < b) {
        while (atomicAdd(&flags[t], 0) == 0) {}
        contrib = atomicAdd(&bsum[t], 0);
    }
    __syncthreads();
    sh[t] = contrib;
    __syncthreads();
    #pragma unroll
    for (int off = 128; off; off >>= 1) {
        if (t < off) sh[t] += sh[t + off];
        __syncthreads();
    }
    int offset = sh[0];
    if (i < N_NODES) {
        int rp = (val - v) + offset;
        rowptr[i] = rp;
        esrc[rp] = i;       // self-loop first
    }
    if (i == 0) rowptr[N_NODES] = E_TOT;
}

// ---- K4: scatter_edges (odd blocks) + gemm xr-half (even blocks) ----
__global__ __launch_bounds__(256)
void k_scatter_gemmxr(const int* __restrict__ ei, const int* __restrict__ rowptr,
                      const unsigned short* __restrict__ rank16, int* __restrict__ esrc,
                      const float* __restrict__ x, const unsigned short* __restrict__ Bp1,
                      float* __restrict__ xr1, int M) {
    int sub = blockIdx.x >> 1;
    if (blockIdx.x & 1) {
        int nz = __syncthreads_or(ei[2 * threadIdx.x + 1]);
        int i = sub * 256 + threadIdx.x;
        if (2 * i >= N_EDGES) return;
        bool has2 = (2 * i + 1 < N_EDGES);
        int s0, d0, s1 = 0, d1 = 0;
        if (nz) {
            int2 sp = *(const int2*)(ei + 2 * i);
            int2 dp = *(const int2*)(ei + N_EDGES + 2 * i);
            s0 = sp.x; s1 = sp.y; d0 = dp.x; d1 = dp.y;
        } else {
            int4 sp = *(const int4*)(ei + 4 * i);
            int4 dp = *(const int4*)(ei + 2 * N_EDGES + 4 * i);
            s0 = sp.x; s1 = sp.z; d0 = dp.x; d1 = dp.z;
        }
        unsigned int rr = *(const unsigned int*)(rank16 + 2 * i);
        esrc[rowptr[d0] + 1 + (int)(rr & 0xffffu)] = s0;
        if (has2) esrc[rowptr[d1] + 1 + (int)(rr >> 16)] = s1;
    } else {
        gemm128_half(sub, x, Bp1 + 128 * 128, nullptr, xr1, M);
    }
}

// ---- MFMA GEMM pair for layer 2 (N=64): C0bf = bf16(A@B0), C1 = A@B1 ----
__global__ __launch_bounds__(256)
void gemm_mfma64(const unsigned short* __restrict__ Abf, const unsigned short* __restrict__ Bp,
                 unsigned short* __restrict__ C0bf, float* __restrict__ C1, int M) {
    int w = threadIdx.x >> 6, lane = threadIdx.x & 63;
    int quad = lane >> 4, l16 = lane & 15;
    int matrix = w >> 1;
    int row0 = blockIdx.x * 32 + (w & 1) * 16;
    const unsigned short* Bm = Bp + matrix * 128 * 64;
    f32x4 acc[4];
    #pragma unroll
    for (int t = 0; t < 4; ++t) acc[t] = (f32x4){0.f, 0.f, 0.f, 0.f};
    int arow = row0 + l16;
    bool aok = arow < M;
    const short* Ap = (const short*)Abf + (size_t)arow * 128 + quad * 8;
    #pragma unroll
    for (int kt = 0; kt < 4; ++kt) {
        short8 a = (short8)0;
        if (aok) a = *(const short8*)(Ap + kt * 32);
        #pragma unroll
        for (int t = 0; t < 4; ++t) {
            const short* bp = (const short*)Bm + (((kt * 4 + t) * 16 + l16) * 4 + quad) * 8;
            short8 bfr = *(const short8*)bp;
            acc[t] = __builtin_amdgcn_mfma_f32_16x16x32_bf16(a, bfr, acc[t], 0, 0, 0);
        }
    }
    #pragma unroll
    for (int t = 0; t < 4; ++t) {
        int col = t * 16 + l16;
        #pragma unroll
        for (int r = 0; r < 4; ++r) {
            int row = row0 + quad * 4 + r;
            if (row < M) {
                if (matrix) C1[(size_t)row * 64 + col] = acc[t][r];
                else        C0bf[(size_t)row * 64 + col] = f2bf(acc[t][r]);
            }
        }
    }
}

// ---------------- Layer 1 (H=8, C=16) ----------------
__global__ __launch_bounds__(256)
void node_fused1(const int* __restrict__ rowptr, const int* __restrict__ esrc,
                 const unsigned short* __restrict__ xlbf, const float* __restrict__ xr,
                 const float* __restrict__ att, const float* __restrict__ b1,
                 unsigned short* __restrict__ hbf) {
    int wave = threadIdx.x >> 6;
    int lane = threadIdx.x & 63;
    int n = blockIdx.x * 4 + wave;            // grid = 12500 exact
    int slot = lane >> 4;                     // 0..3
    int l = lane & 15;                        // channels 8l..8l+7
    int beg = rowptr[n], end = rowptr[n + 1];
    const float* xrp = xr + (size_t)n * 128 + 8 * l;
    float4 xra = *(const float4*)(xrp);
    float4 xrb = *(const float4*)(xrp + 4);
    float4 ata = *(const float4*)(att + 8 * l);
    float4 atb = *(const float4*)(att + 8 * l + 4);
    float den = 0.0f;
    float4 aa = {0, 0, 0, 0}, ab = {0, 0, 0, 0};

    auto body = [&](int k) {
        int s = esrc[k];
        uint4 u = *(const uint4*)(xlbf + (size_t)s * 128 + 8 * l);
        float x0 = bf_lo(u.x), x1 = bf_hi(u.x);
        float x2 = bf_lo(u.y), x3 = bf_hi(u.y);
        float x4 = bf_lo(u.z), x5 = bf_hi(u.z);
        float x6 = bf_lo(u.w), x7 = bf_hi(u.w);
        float v = ata.x * lrelu(x0 + xra.x) + ata.y * lrelu(x1 + xra.y)
                + ata.z * lrelu(x2 + xra.z) + ata.w * lrelu(x3 + xra.w)
                + atb.x * lrelu(x4 + xrb.x) + atb.y * lrelu(x5 + xrb.y)
                + atb.z * lrelu(x6 + xrb.z) + atb.w * lrelu(x7 + xrb.w);
        v += __shfl_xor(v, 1);                // combine the head's two lanes
        float p = __expf(v);
        den += p;
        aa.x += p * x0; aa.y += p * x1; aa.z += p * x2; aa.w += p * x3;
        ab.x += p * x4; ab.y += p * x5; ab.z += p * x6; ab.w += p * x7;
    };
    int k = beg + slot;
    for (; k + 4 < end; k += 8) { body(k); body(k + 4); }
    if (k < end) body(k);

    #pragma unroll
    for (int off = 16; off < 64; off <<= 1) {
        aa.x += __shfl_xor(aa.x, off); aa.y += __shfl_xor(aa.y, off);
        aa.z += __shfl_xor(aa.z, off); aa.w += __shfl_xor(aa.w, off);
        ab.x += __shfl_xor(ab.x, off); ab.y += __shfl_xor(ab.y, off);
        ab.z += __shfl_xor(ab.z, off); ab.w += __shfl_xor(ab.w, off);
        den   += __shfl_xor(den, off);
    }
    if (slot == 0) {
        float inv = 1.0f / (den + SM_EPS);
        float4 b4a = *(const float4*)(b1 + 8 * l);
        float4 b4b = *(const float4*)(b1 + 8 * l + 4);
        float oa0 = fmaxf(aa.x * inv + b4a.x, 0.0f);
        float oa1 = fmaxf(aa.y * inv + b4a.y, 0.0f);
        float oa2 = fmaxf(aa.z * inv + b4a.z, 0.0f);
        float oa3 = fmaxf(aa.w * inv + b4a.w, 0.0f);
        float ob0 = fmaxf(ab.x * inv + b4b.x, 0.0f);
        float ob1 = fmaxf(ab.y * inv + b4b.y, 0.0f);
        float ob2 = fmaxf(ab.z * inv + b4b.z, 0.0f);
        float ob3 = fmaxf(ab.w * inv + b4b.w, 0.0f);
        uint4 pk;
        pk.x = f2bf_pack2(oa0, oa1);
        pk.y = f2bf_pack2(oa2, oa3);
        pk.z = f2bf_pack2(ob0, ob1);
        pk.w = f2bf_pack2(ob2, ob3);
        *(uint4*)(hbf + (size_t)n * 128 + 8 * l) = pk;
    }
}

// ---------------- Layer 2 (H=1, C=64) ----------------
__global__ __launch_bounds__(256)
void node_fused2(const int* __restrict__ rowptr, const int* __restrict__ esrc,
                 const unsigned short* __restrict__ xlbf, const float* __restrict__ xr,
                 const float* __restrict__ att, const float* __restrict__ b2v,
                 float* __restrict__ out_emb) {
    int wave = threadIdx.x >> 6;
    int lane = threadIdx.x & 63;
    int n = blockIdx.x * 4 + wave;
    int slot = lane >> 3;                     // 0..7
    int l = lane & 7;                         // channels 8l..8l+7
    int beg = rowptr[n], end = rowptr[n + 1];
    const float* xrp = xr + (size_t)n * 64 + 8 * l;
    float4 xra = *(const float4*)(xrp);
    float4 xrb = *(const float4*)(xrp + 4);
    float4 ata = *(const float4*)(att + 8 * l);
    float4 atb = *(const float4*)(att + 8 * l + 4);
    float den = 0.0f;
    float4 aa = {0, 0, 0, 0}, ab = {0, 0, 0, 0};

    auto body = [&](int k) {
        int s = esrc[k];
        uint4 u = *(const uint4*)(xlbf + (size_t)s * 64 + 8 * l);
        float x0 = bf_lo(u.x), x1 = bf_hi(u.x);
        float x2 = bf_lo(u.y), x3 = bf_hi(u.y);
        float x4 = bf_lo(u.z), x5 = bf_hi(u.z);
        float x6 = bf_lo(u.w), x7 = bf_hi(u.w);
        float v = ata.x * lrelu(x0 + xra.x) + ata.y * lrelu(x1 + xra.y)
                + ata.z * lrelu(x2 + xra.z) + ata.w * lrelu(x3 + xra.w)
                + atb.x * lrelu(x4 + xrb.x) + atb.y * lrelu(x5 + xrb.y)
                + atb.z * lrelu(x6 + xrb.z) + atb.w * lrelu(x7 + xrb.w);
        v += __shfl_xor(v, 1);
        v += __shfl_xor(v, 2);
        v += __shfl_xor(v, 4);
        float p = __expf(v);
        den += p;
        aa.x += p * x0; aa.y += p * x1; aa.z += p * x2; aa.w += p * x3;
        ab.x += p * x4; ab.y += p * x5; ab.z += p * x6; ab.w += p * x7;
    };
    int k = beg + slot;
    for (; k + 8 < end; k += 16) { body(k); body(k + 8); }
    if (k < end) body(k);

    #pragma unroll
    for (int off = 8; off < 64; off <<= 1) {
        aa.x += __shfl_xor(aa.x, off); aa.y += __shfl_xor(aa.y, off);
        aa.z += __shfl_xor(aa.z, off); aa.w += __shfl_xor(aa.w, off);
        ab.x += __shfl_xor(ab.x, off); ab.y += __shfl_xor(ab.y, off);
        ab.z += __shfl_xor(ab.z, off); ab.w += __shfl_xor(ab.w, off);
        den   += __shfl_xor(den, off);
    }
    if (slot == 0) {
        float inv = 1.0f / (den + SM_EPS);
        float4 b4a = *(const float4*)(b2v + 8 * l);
        float4 b4b = *(const float4*)(b2v + 8 * l + 4);
        float4 ea, eb;
        ea.x = aa.x * inv + b4a.x; ea.y = aa.y * inv + b4a.y;
        ea.z = aa.z * inv + b4a.z; ea.w = aa.w * inv + b4a.w;
        eb.x = ab.x * inv + b4b.x; eb.y = ab.y * inv + b4b.y;
        eb.z = ab.z * inv + b4b.z; eb.w = ab.w * inv + b4b.w;
        float* op = out_emb + (size_t)n * 64 + 8 * l;
        *(float4*)(op)     = ea;
        *(float4*)(op + 4) = eb;
    }
}

// ---------------- Classifier: LDS-tiled ----------------
#define CLS_NODES 32
__global__ __launch_bounds__(256)
void classifier(const float* __restrict__ emb, const float* __restrict__ Wc1,
                const float* __restrict__ bc1, const float* __restrict__ Wc2,
                const float* __restrict__ bc2, float* __restrict__ out_logits) {
    __shared__ float w1[64 * 128];            // 32 KB
    __shared__ float eS[CLS_NODES][64];       // 8 KB
    __shared__ float tS[CLS_NODES][132];      // pad 132 breaks phase-C conflicts
    int t = threadIdx.x;
    int n0 = blockIdx.x * CLS_NODES;
    for (int i = t; i < 64 * 128 / 4; i += 256)
        ((float4*)w1)[i] = ((const float4*)Wc1)[i];
    for (int i = t; i < CLS_NODES * 64 / 4; i += 256) {
        size_t off = (size_t)n0 * 64 + i * 4;
        float4 v = {0, 0, 0, 0};
        if (off + 3 < (size_t)N_NODES * 64) v = *(const float4*)(emb + off);
        ((float4*)eS)[i] = v;
    }
    __syncthreads();
    int jj = t & 127, half = t >> 7;
    for (int nn = half; nn < CLS_NODES; nn += 2) {
        float a0 = 0, a1 = 0, a2 = 0, a3 = 0;
        #pragma unroll
        for (int k = 0; k < 64; k += 4) {
            a0 += eS[nn][k]     * w1[(k)     * 128 + jj];
            a1 += eS[nn][k + 1] * w1[(k + 1) * 128 + jj];
            a2 += eS[nn][k + 2] * w1[(k + 2) * 128 + jj];
            a3 += eS[nn][k + 3] * w1[(k + 3) * 128 + jj];
        }
        tS[nn][jj] = fmaxf(bc1[jj] + (a0 + a1) + (a2 + a3), 0.0f);
    }
    __syncthreads();
    int node = t >> 3, seg = t & 7;
    float v0 = 0, v1 = 0;
    #pragma unroll
    for (int c = 0; c < 16; ++c) {
        float tv = tS[node][seg * 16 + c];
        v0 += tv * Wc2[2 * (seg * 16 + c)];
        v1 += tv * Wc2[2 * (seg * 16 + c) + 1];
    }
    v0 += __shfl_xor(v0, 1); v1 += __shfl_xor(v1, 1);
    v0 += __shfl_xor(v0, 2); v1 += __shfl_xor(v1, 2);
    v0 += __shfl_xor(v0, 4); v1 += __shfl_xor(v1, 4);
    int n = n0 + node;
    if (seg == 0 && n < N_NODES) {
        out_logits[(size_t)n * 2 + 0] = v0 + bc2[0];
        out_logits[(size_t)n * 2 + 1] = v1 + bc2[1];
    }
}

extern "C" void kernel_launch(void* const* d_in, const int* in_sizes, int n_in,
                              void* d_out, int out_size, void* d_ws, size_t ws_size,
                              hipStream_t stream) {
    const float* x    = (const float*)d_in[0];
    const int*   ei   = (const int*)d_in[1];
    const float* Wl1  = (const float*)d_in[3];
    const float* Wr1  = (const float*)d_in[4];
    const float* att1 = (const float*)d_in[5];
    const float* b1   = (const float*)d_in[6];
    const float* Wl2  = (const float*)d_in[7];
    const float* Wr2  = (const float*)d_in[8];
    const float* att2 = (const float*)d_in[9];
    const float* b2   = (const float*)d_in[10];
    const float* Wc1  = (const float*)d_in[15];
    const float* bc1  = (const float*)d_in[16];
    const float* Wc2  = (const float*)d_in[17];
    const float* bc2  = (const float*)d_in[18];

    float* ws = (float*)d_ws;
    int* deg    = (int*)ws;                        //      0 .. 50000
    int* rowptr = deg + 50000;                     //  50000 .. 100016
    int* esrc   = rowptr + 50016;                  // 100016 .. 950016
    int* bsum   = esrc + 850000;                   // 950016 .. 950272
    int* flags  = bsum + 256;                      // 950272 .. 950528
    unsigned short* rank16 = (unsigned short*)(flags + 256);   // 400000 words
    float* xr1          = ws + 1400448;                        // 6.4M words (layer2 xr2 in first 3.2M)
    unsigned short* xlbf = (unsigned short*)(ws + 7800448);    // 3.2M words (layer2 xl2 reuses)
    unsigned short* hbf  = (unsigned short*)(ws + 11000448);   // 3.2M words
    unsigned short* Bp1  = (unsigned short*)(ws + 14200448);   // 16384 words
    unsigned short* Bp2  = (unsigned short*)(ws + 14216832);   // 8192 words

    float* out_emb    = (float*)d_out;
    float* out_logits = out_emb + (size_t)N_NODES * 64;

    // ---- prep: pack weights, zero deg + flags ----
    prep<<<389, 256, 0, stream>>>(Wl1, Wr1, Wl2, Wr2, Bp1, Bp2, deg, flags);

    // ---- K2: count_deg ⊕ gemm xl-half (interleaved grids) ----
    k_count_gemmxl<<<3126, 256, 0, stream>>>(ei, deg, rank16, x, Bp1, xlbf, N_NODES);

    // ---- scan ----
    scan_fused<<<SCAN_B, 256, 0, stream>>>(deg, rowptr, esrc, bsum, flags);

    // ---- K4: scatter ⊕ gemm xr-half ----
    k_scatter_gemmxr<<<3126, 256, 0, stream>>>(ei, rowptr, rank16, esrc, x, Bp1, xr1, N_NODES);

    // ---- layer 1 node pass ----
    node_fused1<<<12500, 256, 0, stream>>>(rowptr, esrc, xlbf, xr1, att1, b1, hbf);

    // ---- layer 2 ----
    gemm_mfma64<<<1563, 256, 0, stream>>>(hbf, Bp2, xlbf, xr1, N_NODES);
    node_fused2<<<12500, 256, 0, stream>>>(rowptr, esrc, xlbf, xr1, att2, b2, out_emb);

    // ---- classifier ----
    classifier<<<1563, 256, 0, stream>>>(out_emb, Wc1, bc1, Wc2, bc2, out_logits);
}

// Round 18
// 300.262 us; speedup vs baseline: 1.4022x; 1.0858x over previous
//
#include <hip/hip_runtime.h>
#include <hip/hip_bf16.h>
#include <cfloat>

#define N_NODES 50000
#define N_EDGES 800000
#define E_TOT   850000   /* edges + self-loops */
#define NEG_SLOPE 0.2f
#define SM_EPS 1e-16f
#define SCAN_B 196       /* ceil(50000/256) */
#define LOG2E 1.4426950408889634f

typedef __attribute__((ext_vector_type(8))) short short8;
typedef __attribute__((ext_vector_type(4))) float f32x4;

__device__ __forceinline__ float lrelu(float v) { return v > 0.0f ? v : NEG_SLOPE * v; }

// fp32 -> bf16 (RNE) pack / unpack helpers
__device__ __forceinline__ unsigned f2bf_pack2(float a, float b) {
    unsigned ua = __float_as_uint(a);
    ua += 0x7fff + ((ua >> 16) & 1);
    unsigned ub = __float_as_uint(b);
    ub += 0x7fff + ((ub >> 16) & 1);
    return (ua >> 16) | (ub & 0xffff0000u);
}
__device__ __forceinline__ unsigned short f2bf(float a) {
    unsigned ua = __float_as_uint(a);
    ua += 0x7fff + ((ua >> 16) & 1);
    return (unsigned short)(ua >> 16);
}
__device__ __forceinline__ float bf_lo(unsigned u) { return __uint_as_float(u << 16); }
__device__ __forceinline__ float bf_hi(unsigned u) { return __uint_as_float(u & 0xffff0000u); }

// ---- prep: pack Bp1/Bp2/Wc1p into MFMA B lane order; zero deg + flags ----
__device__ __forceinline__ unsigned short pack_one(const float* __restrict__ B0,
                                                   const float* __restrict__ B1,
                                                   int i, int N) {
    int m   = i / (128 * N);
    int rem = i % (128 * N);
    int j    = rem & 7;
    int quad = (rem >> 3) & 3;
    int n    = (rem >> 5) & 15;
    int ctk  = rem >> 9;
    int ct   = ctk % (N / 16);
    int kt   = ctk / (N / 16);
    int k    = kt * 32 + quad * 8 + j;
    int col  = ct * 16 + n;
    const float* B = m ? B1 : B0;
    return f2bf(B[k * N + col]);
}

__global__ void prep(const float* __restrict__ Wl1, const float* __restrict__ Wr1,
                     const float* __restrict__ Wl2, const float* __restrict__ Wr2,
                     const float* __restrict__ Wc1,
                     unsigned short* __restrict__ Bp1, unsigned short* __restrict__ Bp2,
                     unsigned short* __restrict__ Wc1p,
                     int* __restrict__ deg, int* __restrict__ flags) {
    int i = blockIdx.x * 256 + threadIdx.x;
    if (i < 32768) {
        Bp1[i] = pack_one(Wl1, Wr1, i, 128);
    } else if (i < 49152) {
        Bp2[i - 32768] = pack_one(Wl2, Wr2, i - 32768, 64);
    } else if (i < 57344) {
        // Wc1 [64][128] -> B fragments, K=64 (kt<2), N=128
        int idx = i - 49152;
        int j    = idx & 7;
        int quad = (idx >> 3) & 3;
        int n    = (idx >> 5) & 15;
        int ctk  = idx >> 9;
        int ct   = ctk & 7;
        int kt   = ctk >> 3;
        Wc1p[idx] = f2bf(Wc1[(kt * 32 + quad * 8 + j) * 128 + ct * 16 + n]);
    } else if (i < 107344) {
        deg[i - 57344] = 0;
    } else if (i < 107600) {
        flags[i - 107344] = 0;
    }
}

// ---- GEMM wave body: one matrix half of layer-1 GEMM (N=128, A fp32 in-reg converted) ----
__device__ __forceinline__ void gemm128_half(int b, const float* __restrict__ x,
                                             const unsigned short* __restrict__ Bm,
                                             unsigned short* __restrict__ Cbf,
                                             float* __restrict__ Cf, int M) {
    int w = threadIdx.x >> 6, lane = threadIdx.x & 63;
    int quad = lane >> 4, l16 = lane & 15;
    int row0 = b * 32 + (w & 1) * 16;
    int cb   = (w >> 1) * 64;
    f32x4 acc[4];
    #pragma unroll
    for (int t = 0; t < 4; ++t) acc[t] = (f32x4){0.f, 0.f, 0.f, 0.f};
    int arow = row0 + l16;
    bool aok = arow < M;
    #pragma unroll
    for (int kt = 0; kt < 4; ++kt) {
        short8 a = (short8)0;
        if (aok) {
            const float* Ap = x + (size_t)arow * 128 + quad * 8 + kt * 32;
            float4 f0 = *(const float4*)(Ap);
            float4 f1 = *(const float4*)(Ap + 4);
            union { uint4 u; short8 s; } cv;
            cv.u.x = f2bf_pack2(f0.x, f0.y);
            cv.u.y = f2bf_pack2(f0.z, f0.w);
            cv.u.z = f2bf_pack2(f1.x, f1.y);
            cv.u.w = f2bf_pack2(f1.z, f1.w);
            a = cv.s;
        }
        #pragma unroll
        for (int t = 0; t < 4; ++t) {
            int ct = (cb >> 4) + t;
            const short* bp = (const short*)Bm + (((kt * 8 + ct) * 16 + l16) * 4 + quad) * 8;
            short8 bfr = *(const short8*)bp;
            acc[t] = __builtin_amdgcn_mfma_f32_16x16x32_bf16(a, bfr, acc[t], 0, 0, 0);
        }
    }
    #pragma unroll
    for (int t = 0; t < 4; ++t) {
        int col = cb + t * 16 + l16;
        #pragma unroll
        for (int r = 0; r < 4; ++r) {
            int row = row0 + quad * 4 + r;
            if (row < M) {
                if (Cbf) Cbf[(size_t)row * 128 + col] = f2bf(acc[t][r]);
                else     Cf[(size_t)row * 128 + col]  = acc[t][r];
            }
        }
    }
}

// ---- K2: count_deg ⊕ gemm-xl ⊕ gemm-xr, 3-way interleaved grid ----
__global__ __launch_bounds__(256)
void k2_count_gemms(const int* __restrict__ ei, int* __restrict__ deg,
                    unsigned short* __restrict__ rank16,
                    const float* __restrict__ x, const unsigned short* __restrict__ Bp1,
                    unsigned short* __restrict__ xlbf, float* __restrict__ xr1, int M) {
    int kind = blockIdx.x % 3;
    int sub  = blockIdx.x / 3;
    if (kind == 1) {
        int nz = __syncthreads_or(ei[2 * threadIdx.x + 1]);   // 0 => int64 layout
        int i = sub * 256 + threadIdx.x;
        if (2 * i >= N_EDGES) return;
        bool has2 = (2 * i + 1 < N_EDGES);
        int d0, d1 = 0;
        if (nz) {
            int2 dp = *(const int2*)(ei + N_EDGES + 2 * i);
            d0 = dp.x; d1 = dp.y;
        } else {
            int4 dp = *(const int4*)(ei + 2 * N_EDGES + 4 * i);
            d0 = dp.x; d1 = dp.z;
        }
        unsigned short r0 = (unsigned short)atomicAdd(&deg[d0], 1);
        unsigned short r1 = 0;
        if (has2) r1 = (unsigned short)atomicAdd(&deg[d1], 1);
        *(unsigned int*)(rank16 + 2 * i) = (unsigned int)r0 | ((unsigned int)r1 << 16);
    } else if (kind == 0) {
        gemm128_half(sub, x, Bp1, xlbf, nullptr, M);
    } else {
        gemm128_half(sub, x, Bp1 + 128 * 128, nullptr, xr1, M);
    }
}

// ---- scan (fused; publish/spin over block sums) ----
__global__ void scan_fused(const int* __restrict__ deg, int* __restrict__ rowptr,
                           int* __restrict__ esrc, int* __restrict__ bsum,
                           int* __restrict__ flags) {
    __shared__ int sh[256];
    int b = blockIdx.x, t = threadIdx.x, i = b * 256 + t;
    int v = (i < N_NODES) ? deg[i] + 1 : 0;
    sh[t] = v;
    __syncthreads();
    int val = v;
    for (int off = 1; off < 256; off <<= 1) {
        int add = (t >= off) ? sh[t - off] : 0;
        __syncthreads();
        val += add; sh[t] = val;
        __syncthreads();
    }
    if (t == 255) {
        bsum[b] = val;
        __threadfence();
        atomicExch(&flags[b], 1);
    }
    int contrib = 0;
    if (t < b) {
        while (atomicAdd(&flags[t], 0) == 0) {}
        contrib = atomicAdd(&bsum[t], 0);
    }
    __syncthreads();
    sh[t] = contrib;
    __syncthreads();
    #pragma unroll
    for (int off = 128; off; off >>= 1) {
        if (t < off) sh[t] += sh[t + off];
        __syncthreads();
    }
    int offset = sh[0];
    if (i < N_NODES) {
        int rp = (val - v) + offset;
        rowptr[i] = rp;
        esrc[rp] = i;       // self-loop first
    }
    if (i == 0) rowptr[N_NODES] = E_TOT;
}

// ---- scatter: no atomics, position = rowptr[dst] + 1 + rank ----
__global__ void scatter_edges(const int* __restrict__ ei, const int* __restrict__ rowptr,
                              const unsigned short* __restrict__ rank16,
                              int* __restrict__ esrc) {
    int nz = __syncthreads_or(ei[2 * threadIdx.x + 1]);
    int i = blockIdx.x * blockDim.x + threadIdx.x;
    if (2 * i >= N_EDGES) return;
    bool has2 = (2 * i + 1 < N_EDGES);
    int s0, d0, s1 = 0, d1 = 0;
    if (nz) {
        int2 sp = *(const int2*)(ei + 2 * i);
        int2 dp = *(const int2*)(ei + N_EDGES + 2 * i);
        s0 = sp.x; s1 = sp.y; d0 = dp.x; d1 = dp.y;
    } else {
        int4 sp = *(const int4*)(ei + 4 * i);
        int4 dp = *(const int4*)(ei + 2 * N_EDGES + 4 * i);
        s0 = sp.x; s1 = sp.z; d0 = dp.x; d1 = dp.z;
    }
    unsigned int rr = *(const unsigned int*)(rank16 + 2 * i);
    esrc[rowptr[d0] + 1 + (int)(rr & 0xffffu)] = s0;
    if (has2) esrc[rowptr[d1] + 1 + (int)(rr >> 16)] = s1;
}

// ---- layer 2 GEMM (N=64): C0bf = bf16(A@B0), C1 = A@B1 (fp32) ----
__global__ __launch_bounds__(256)
void gemm_mfma64(const unsigned short* __restrict__ Abf, const unsigned short* __restrict__ Bp,
                 unsigned short* __restrict__ C0bf, float* __restrict__ C1, int M) {
    int w = threadIdx.x >> 6, lane = threadIdx.x & 63;
    int quad = lane >> 4, l16 = lane & 15;
    int matrix = w >> 1;
    int row0 = blockIdx.x * 32 + (w & 1) * 16;
    const unsigned short* Bm = Bp + matrix * 128 * 64;
    f32x4 acc[4];
    #pragma unroll
    for (int t = 0; t < 4; ++t) acc[t] = (f32x4){0.f, 0.f, 0.f, 0.f};
    int arow = row0 + l16;
    bool aok = arow < M;
    const short* Ap = (const short*)Abf + (size_t)arow * 128 + quad * 8;
    #pragma unroll
    for (int kt = 0; kt < 4; ++kt) {
        short8 a = (short8)0;
        if (aok) a = *(const short8*)(Ap + kt * 32);
        #pragma unroll
        for (int t = 0; t < 4; ++t) {
            const short* bp = (const short*)Bm + (((kt * 4 + t) * 16 + l16) * 4 + quad) * 8;
            short8 bfr = *(const short8*)bp;
            acc[t] = __builtin_amdgcn_mfma_f32_16x16x32_bf16(a, bfr, acc[t], 0, 0, 0);
        }
    }
    #pragma unroll
    for (int t = 0; t < 4; ++t) {
        int col = t * 16 + l16;
        #pragma unroll
        for (int r = 0; r < 4; ++r) {
            int row = row0 + quad * 4 + r;
            if (row < M) {
                if (matrix) C1[(size_t)row * 64 + col] = acc[t][r];
                else        C0bf[(size_t)row * 64 + col] = f2bf(acc[t][r]);
            }
        }
    }
}

// ---------------- Layer 1 (H=8, C=16) ----------------
__global__ __launch_bounds__(256)
void node_fused1(const int* __restrict__ rowptr, const int* __restrict__ esrc,
                 const unsigned short* __restrict__ xlbf, const float* __restrict__ xr,
                 const float* __restrict__ att, const float* __restrict__ b1,
                 unsigned short* __restrict__ hbf) {
    int wave = threadIdx.x >> 6;
    int lane = threadIdx.x & 63;
    int n = blockIdx.x * 4 + wave;            // grid = 12500 exact
    int slot = lane >> 4;                     // 0..3
    int l = lane & 15;                        // channels 8l..8l+7
    int beg = rowptr[n], end = rowptr[n + 1];
    const float* xrp = xr + (size_t)n * 128 + 8 * l;
    float4 xra = *(const float4*)(xrp);
    float4 xrb = *(const float4*)(xrp + 4);
    float4 ata = *(const float4*)(att + 8 * l);
    float4 atb = *(const float4*)(att + 8 * l + 4);
    // fold log2(e) into att so exp2f is a bare v_exp_f32
    ata.x *= LOG2E; ata.y *= LOG2E; ata.z *= LOG2E; ata.w *= LOG2E;
    atb.x *= LOG2E; atb.y *= LOG2E; atb.z *= LOG2E; atb.w *= LOG2E;
    float den = 0.0f;
    float4 aa = {0, 0, 0, 0}, ab = {0, 0, 0, 0};

    auto body = [&](int k) {
        int s = esrc[k];
        uint4 u = *(const uint4*)(xlbf + (size_t)s * 128 + 8 * l);
        float x0 = bf_lo(u.x), x1 = bf_hi(u.x);
        float x2 = bf_lo(u.y), x3 = bf_hi(u.y);
        float x4 = bf_lo(u.z), x5 = bf_hi(u.z);
        float x6 = bf_lo(u.w), x7 = bf_hi(u.w);
        float v = ata.x * lrelu(x0 + xra.x) + ata.y * lrelu(x1 + xra.y)
                + ata.z * lrelu(x2 + xra.z) + ata.w * lrelu(x3 + xra.w)
                + atb.x * lrelu(x4 + xrb.x) + atb.y * lrelu(x5 + xrb.y)
                + atb.z * lrelu(x6 + xrb.z) + atb.w * lrelu(x7 + xrb.w);
        v += __shfl_xor(v, 1);                // combine the head's two lanes
        float p = exp2f(v);
        den += p;
        aa.x += p * x0; aa.y += p * x1; aa.z += p * x2; aa.w += p * x3;
        ab.x += p * x4; ab.y += p * x5; ab.z += p * x6; ab.w += p * x7;
    };
    int k = beg + slot;
    for (; k + 4 < end; k += 8) { body(k); body(k + 4); }
    if (k < end) body(k);

    #pragma unroll
    for (int off = 16; off < 64; off <<= 1) {
        aa.x += __shfl_xor(aa.x, off); aa.y += __shfl_xor(aa.y, off);
        aa.z += __shfl_xor(aa.z, off); aa.w += __shfl_xor(aa.w, off);
        ab.x += __shfl_xor(ab.x, off); ab.y += __shfl_xor(ab.y, off);
        ab.z += __shfl_xor(ab.z, off); ab.w += __shfl_xor(ab.w, off);
        den   += __shfl_xor(den, off);
    }
    if (slot == 0) {
        float inv = 1.0f / (den + SM_EPS);
        float4 b4a = *(const float4*)(b1 + 8 * l);
        float4 b4b = *(const float4*)(b1 + 8 * l + 4);
        float oa0 = fmaxf(aa.x * inv + b4a.x, 0.0f);
        float oa1 = fmaxf(aa.y * inv + b4a.y, 0.0f);
        float oa2 = fmaxf(aa.z * inv + b4a.z, 0.0f);
        float oa3 = fmaxf(aa.w * inv + b4a.w, 0.0f);
        float ob0 = fmaxf(ab.x * inv + b4b.x, 0.0f);
        float ob1 = fmaxf(ab.y * inv + b4b.y, 0.0f);
        float ob2 = fmaxf(ab.z * inv + b4b.z, 0.0f);
        float ob3 = fmaxf(ab.w * inv + b4b.w, 0.0f);
        uint4 pk;
        pk.x = f2bf_pack2(oa0, oa1);
        pk.y = f2bf_pack2(oa2, oa3);
        pk.z = f2bf_pack2(ob0, ob1);
        pk.w = f2bf_pack2(ob2, ob3);
        *(uint4*)(hbf + (size_t)n * 128 + 8 * l) = pk;
    }
}

// ---------------- Layer 2 (H=1, C=64) — also writes bf16 emb for classifier ----------------
__global__ __launch_bounds__(256)
void node_fused2(const int* __restrict__ rowptr, const int* __restrict__ esrc,
                 const unsigned short* __restrict__ xlbf, const float* __restrict__ xr,
                 const float* __restrict__ att, const float* __restrict__ b2v,
                 float* __restrict__ out_emb, unsigned short* __restrict__ embbf) {
    int wave = threadIdx.x >> 6;
    int lane = threadIdx.x & 63;
    int n = blockIdx.x * 4 + wave;
    int slot = lane >> 3;                     // 0..7
    int l = lane & 7;                         // channels 8l..8l+7
    int beg = rowptr[n], end = rowptr[n + 1];
    const float* xrp = xr + (size_t)n * 64 + 8 * l;
    float4 xra = *(const float4*)(xrp);
    float4 xrb = *(const float4*)(xrp + 4);
    float4 ata = *(const float4*)(att + 8 * l);
    float4 atb = *(const float4*)(att + 8 * l + 4);
    ata.x *= LOG2E; ata.y *= LOG2E; ata.z *= LOG2E; ata.w *= LOG2E;
    atb.x *= LOG2E; atb.y *= LOG2E; atb.z *= LOG2E; atb.w *= LOG2E;
    float den = 0.0f;
    float4 aa = {0, 0, 0, 0}, ab = {0, 0, 0, 0};

    auto body = [&](int k) {
        int s = esrc[k];
        uint4 u = *(const uint4*)(xlbf + (size_t)s * 64 + 8 * l);
        float x0 = bf_lo(u.x), x1 = bf_hi(u.x);
        float x2 = bf_lo(u.y), x3 = bf_hi(u.y);
        float x4 = bf_lo(u.z), x5 = bf_hi(u.z);
        float x6 = bf_lo(u.w), x7 = bf_hi(u.w);
        float v = ata.x * lrelu(x0 + xra.x) + ata.y * lrelu(x1 + xra.y)
                + ata.z * lrelu(x2 + xra.z) + ata.w * lrelu(x3 + xra.w)
                + atb.x * lrelu(x4 + xrb.x) + atb.y * lrelu(x5 + xrb.y)
                + atb.z * lrelu(x6 + xrb.z) + atb.w * lrelu(x7 + xrb.w);
        v += __shfl_xor(v, 1);
        v += __shfl_xor(v, 2);
        v += __shfl_xor(v, 4);
        float p = exp2f(v);
        den += p;
        aa.x += p * x0; aa.y += p * x1; aa.z += p * x2; aa.w += p * x3;
        ab.x += p * x4; ab.y += p * x5; ab.z += p * x6; ab.w += p * x7;
    };
    int k = beg + slot;
    for (; k + 8 < end; k += 16) { body(k); body(k + 8); }
    if (k < end) body(k);

    #pragma unroll
    for (int off = 8; off < 64; off <<= 1) {
        aa.x += __shfl_xor(aa.x, off); aa.y += __shfl_xor(aa.y, off);
        aa.z += __shfl_xor(aa.z, off); aa.w += __shfl_xor(aa.w, off);
        ab.x += __shfl_xor(ab.x, off); ab.y += __shfl_xor(ab.y, off);
        ab.z += __shfl_xor(ab.z, off); ab.w += __shfl_xor(ab.w, off);
        den   += __shfl_xor(den, off);
    }
    if (slot == 0) {
        float inv = 1.0f / (den + SM_EPS);
        float4 b4a = *(const float4*)(b2v + 8 * l);
        float4 b4b = *(const float4*)(b2v + 8 * l + 4);
        float4 ea, eb;
        ea.x = aa.x * inv + b4a.x; ea.y = aa.y * inv + b4a.y;
        ea.z = aa.z * inv + b4a.z; ea.w = aa.w * inv + b4a.w;
        eb.x = ab.x * inv + b4b.x; eb.y = ab.y * inv + b4b.y;
        eb.z = ab.z * inv + b4b.z; eb.w = ab.w * inv + b4b.w;
        float* op = out_emb + (size_t)n * 64 + 8 * l;
        *(float4*)(op)     = ea;
        *(float4*)(op + 4) = eb;
        uint4 pk;
        pk.x = f2bf_pack2(ea.x, ea.y);
        pk.y = f2bf_pack2(ea.z, ea.w);
        pk.z = f2bf_pack2(eb.x, eb.y);
        pk.w = f2bf_pack2(eb.z, eb.w);
        *(uint4*)(embbf + (size_t)n * 64 + 8 * l) = pk;
    }
}

// ---------------- Classifier via MFMA ----------------
__global__ __launch_bounds__(256)
void cls_mfma(const unsigned short* __restrict__ embbf, const unsigned short* __restrict__ Wc1p,
              const float* __restrict__ bc1, const float* __restrict__ Wc2,
              const float* __restrict__ bc2, float* __restrict__ out_logits) {
    __shared__ float part[2][16][2][2];       // [rowhalf][row16][colhalf][class]
    int w = threadIdx.x >> 6, lane = threadIdx.x & 63;
    int quad = lane >> 4, l16 = lane & 15;
    int rowhalf = w & 1, colhalf = w >> 1;
    int row0 = blockIdx.x * 32 + rowhalf * 16;
    int cb = colhalf * 64;
    f32x4 acc[4];
    #pragma unroll
    for (int t = 0; t < 4; ++t) acc[t] = (f32x4){0.f, 0.f, 0.f, 0.f};
    int arow = row0 + l16;
    bool aok = arow < N_NODES;
    const short* Ap = (const short*)embbf + (size_t)arow * 64 + quad * 8;
    #pragma unroll
    for (int kt = 0; kt < 2; ++kt) {
        short8 a = (short8)0;
        if (aok) a = *(const short8*)(Ap + kt * 32);
        #pragma unroll
        for (int t = 0; t < 4; ++t) {
            int ct = colhalf * 4 + t;
            const short* bp = (const short*)Wc1p + (((kt * 8 + ct) * 16 + l16) * 4 + quad) * 8;
            short8 bfr = *(const short8*)bp;
            acc[t] = __builtin_amdgcn_mfma_f32_16x16x32_bf16(a, bfr, acc[t], 0, 0, 0);
        }
    }
    float p0[4] = {0, 0, 0, 0}, p1[4] = {0, 0, 0, 0};
    #pragma unroll
    for (int t = 0; t < 4; ++t) {
        int col = cb + t * 16 + l16;
        float w2a = Wc2[2 * col], w2b = Wc2[2 * col + 1];
        float bc = bc1[col];
        #pragma unroll
        for (int r = 0; r < 4; ++r) {
            float tv = fmaxf(acc[t][r] + bc, 0.0f);
            p0[r] += tv * w2a;
            p1[r] += tv * w2b;
        }
    }
    #pragma unroll
    for (int off = 1; off < 16; off <<= 1) {
        #pragma unroll
        for (int r = 0; r < 4; ++r) {
            p0[r] += __shfl_xor(p0[r], off);
            p1[r] += __shfl_xor(p1[r], off);
        }
    }
    if (l16 == 0) {
        #pragma unroll
        for (int r = 0; r < 4; ++r) {
            part[rowhalf][quad * 4 + r][colhalf][0] = p0[r];
            part[rowhalf][quad * 4 + r][colhalf][1] = p1[r];
        }
    }
    __syncthreads();
    int t = threadIdx.x;
    if (t < 64) {
        int row = t >> 1, c = t & 1;
        int rh = row >> 4, r16 = row & 15;
        float s = part[rh][r16][0][c] + part[rh][r16][1][c] + bc2[c];
        int n = blockIdx.x * 32 + row;
        if (n < N_NODES) out_logits[(size_t)n * 2 + c] = s;
    }
}

extern "C" void kernel_launch(void* const* d_in, const int* in_sizes, int n_in,
                              void* d_out, int out_size, void* d_ws, size_t ws_size,
                              hipStream_t stream) {
    const float* x    = (const float*)d_in[0];
    const int*   ei   = (const int*)d_in[1];
    const float* Wl1  = (const float*)d_in[3];
    const float* Wr1  = (const float*)d_in[4];
    const float* att1 = (const float*)d_in[5];
    const float* b1   = (const float*)d_in[6];
    const float* Wl2  = (const float*)d_in[7];
    const float* Wr2  = (const float*)d_in[8];
    const float* att2 = (const float*)d_in[9];
    const float* b2   = (const float*)d_in[10];
    const float* Wc1  = (const float*)d_in[15];
    const float* bc1  = (const float*)d_in[16];
    const float* Wc2  = (const float*)d_in[17];
    const float* bc2  = (const float*)d_in[18];

    float* ws = (float*)d_ws;
    int* deg    = (int*)ws;                        //      0 .. 50000
    int* rowptr = deg + 50000;                     //  50000 .. 100016
    int* esrc   = rowptr + 50016;                  // 100016 .. 950016
    int* bsum   = esrc + 850000;                   // 950016 .. 950272
    int* flags  = bsum + 256;                      // 950272 .. 950528
    unsigned short* rank16 = (unsigned short*)(flags + 256);   // 400000 words
    float* xr1           = ws + 1400448;                       // 6.4M words (layer2 xr2 in first 3.2M)
    unsigned short* xlbf = (unsigned short*)(ws + 7800448);    // 3.2M words (layer2 xl2 reuses)
    unsigned short* hbf  = (unsigned short*)(ws + 11000448);   // 3.2M words
    // CORRECTED sizes (units = 4B words): Bp1 = 32768 bf16 = 16384 words,
    // Bp2 = 16384 bf16 = 8192 words, Wc1p = 8192 bf16 = 4096 words.
    unsigned short* Bp1   = (unsigned short*)(ws + 14200448);  // .. 14216832
    unsigned short* Bp2   = (unsigned short*)(ws + 14216832);  // .. 14225024
    unsigned short* Wc1p  = (unsigned short*)(ws + 14225024);  // .. 14229120
    unsigned short* embbf = (unsigned short*)(ws + 14229120);  // 1.6M words
    // total ≈ 15.83M words ≈ 63 MB

    float* out_emb    = (float*)d_out;
    float* out_logits = out_emb + (size_t)N_NODES * 64;

    // ---- prep: pack Bp1/Bp2/Wc1p, zero deg + flags ----
    prep<<<421, 256, 0, stream>>>(Wl1, Wr1, Wl2, Wr2, Wc1, Bp1, Bp2, Wc1p, deg, flags);

    // ---- K2: count ⊕ gemm-xl ⊕ gemm-xr ----
    k2_count_gemms<<<4689, 256, 0, stream>>>(ei, deg, rank16, x, Bp1, xlbf, xr1, N_NODES);

    // ---- scan ----
    scan_fused<<<SCAN_B, 256, 0, stream>>>(deg, rowptr, esrc, bsum, flags);

    // ---- scatter (atomic-free) ----
    scatter_edges<<<1563, 256, 0, stream>>>(ei, rowptr, rank16, esrc);

    // ---- layer 1 node pass ----
    node_fused1<<<12500, 256, 0, stream>>>(rowptr, esrc, xlbf, xr1, att1, b1, hbf);

    // ---- layer 2 ----
    gemm_mfma64<<<1563, 256, 0, stream>>>(hbf, Bp2, xlbf, xr1, N_NODES);
    node_fused2<<<12500, 256, 0, stream>>>(rowptr, esrc, xlbf, xr1, att2, b2, out_emb, embbf);

    // ---- classifier (MFMA) ----
    cls_mfma<<<1563, 256, 0, stream>>>(embbf, Wc1p, bc1, Wc2, bc2, out_logits);
}